// Round 9
// baseline (10599.449 us; speedup 1.0000x reference)
//
#include <hip/hip_runtime.h>

// ============================================================================
// RSSM (DynamicsModel) on MI355X — round 9.
// Ledger: r2 6.64 / r5 6.72 / r7 6.57 / r8 6.79 — all in-kernel opts flat at
// ~104us/step => suspect fixed per-dispatch cost (~8-12us).  This round: 4
// dispatches/step from individually-proven kernels:
//   1. sa (r8 gemm_n64 exact)           2. gigh_gru (r7 exact, h ping-pong)
//   3. ha/ho unsplit n64 + Ci+ReLU      4. prpo + fused rsample (r6 kernel)
// Outcome decides: ~5ms => keep fusing; ~6.5 => in-kernel chains; >=8 =>
// r6's culprit = unsplit/fused tail, revert.
// ============================================================================

typedef __attribute__((ext_vector_type(8))) short bf16x8;
typedef __attribute__((ext_vector_type(4))) float f32x4;
typedef __attribute__((ext_vector_type(4))) short s16x4;

#define DEVI static __device__ __forceinline__

DEVI float bf2f(short s) { union { float f; unsigned u; } v; v.u = ((unsigned)(unsigned short)s) << 16; return v.f; }
DEVI short f2bf(float f) {
  union { float f; unsigned u; } v; v.f = f;
  unsigned r = v.u + 0x7FFFu + ((v.u >> 16) & 1u);   // RNE
  return (short)(r >> 16);
}

#define Bsz 256
#define Tsz 64
#define Hsz 2048
#define Ssz 512
#define Asz 64
#define Esz 2048
#define TM1 63

#define OUT_PS  33554432L
#define OUT_QS  41943040L
#define OUT_PM  50331648L
#define OUT_PLV 58589184L
#define OUT_QM  66846720L
#define OUT_QLV 75104256L

struct GArg {
  const short* A; const short* Bt; const float* bias; const short* Ci;
  float* oF; short* oB;
  int lda, ldb, ldoF, ldoB; long ldci, pstride;
};

// ---------------------------------------------------------------------------
// Scan GEMM (r8-proven): C[256,N] = A[256,K] @ Bt[N,K]^T.  Tile 256x64,
// BK=64, LDS 80KB dbuf, vmcnt(10), XOR-swizzle via pre-swizzled source.
// blockIdx.x = n-block; blockIdx.z: gemm = glog?(z&1):0, kc = z>>glog.
// ---------------------------------------------------------------------------
template<int HASBIAS, int HASCI, int RELU, int OUTF, int OUTB>
__global__ __launch_bounds__(256) void gemm_n64(GArg g0, GArg g1, int glog, int kcK) {
  const int z = blockIdx.z;
  const int gemm = glog ? (z & 1) : 0;
  const int kc = z >> glog;
  const GArg g = gemm ? g1 : g0;
  const short* __restrict__ Ag = g.A + (long)kc * kcK;
  const short* __restrict__ Bg = g.Bt + (long)kc * kcK;
  __shared__ __align__(16) short As[2][16384];
  __shared__ __align__(16) short Bs[2][4096];
  const int tid = threadIdx.x;
  const int w = tid >> 6, l = tid & 63;
  const int bn0 = blockIdx.x << 6;
  const int fc = l & 15, fh = l >> 4;
  const int wr = w << 6;
  const int rx = fc & 7;
  const int srccol = ((l & 7) ^ ((l >> 3) & 7)) << 3;

  long aoff[8], boff[2];
#pragma unroll
  for (int i = 0; i < 8; ++i) {
    const int row = (((i << 2) + w) << 3) + (l >> 3);
    aoff[i] = (long)row * g.lda + srccol;
  }
#pragma unroll
  for (int i = 0; i < 2; ++i) {
    const int row = (((i << 2) + w) << 3) + (l >> 3);
    boff[i] = (long)(bn0 + row) * g.ldb + srccol;
  }

  f32x4 acc[4][4];
#pragma unroll
  for (int i = 0; i < 4; ++i)
#pragma unroll
    for (int j = 0; j < 4; ++j) acc[i][j] = f32x4{0.f, 0.f, 0.f, 0.f};

  auto STAGE = [&](int kt, int buf) {
#pragma unroll
    for (int i = 0; i < 8; ++i) {
      const int ib = ((i << 2) + w) << 10;
      __builtin_amdgcn_global_load_lds(
          (const __attribute__((address_space(1))) void*)(Ag + aoff[i] + (kt << 6)),
          (__attribute__((address_space(3))) void*)((char*)&As[buf][0] + ib), 16, 0, 0);
    }
#pragma unroll
    for (int i = 0; i < 2; ++i) {
      const int ib = ((i << 2) + w) << 10;
      __builtin_amdgcn_global_load_lds(
          (const __attribute__((address_space(1))) void*)(Bg + boff[i] + (kt << 6)),
          (__attribute__((address_space(3))) void*)((char*)&Bs[buf][0] + ib), 16, 0, 0);
    }
  };
  auto COMPUTE = [&](int buf) {
#pragma unroll
    for (int kk = 0; kk < 2; ++kk) {
      const int sw = (((kk << 2) + fh) ^ rx) << 3;
      bf16x8 af[4], bb[4];
#pragma unroll
      for (int mi = 0; mi < 4; ++mi)
        af[mi] = *(const bf16x8*)&As[buf][(wr + (mi << 4) + fc) * 64 + sw];
#pragma unroll
      for (int ni = 0; ni < 4; ++ni)
        bb[ni] = *(const bf16x8*)&Bs[buf][((ni << 4) + fc) * 64 + sw];
#pragma unroll
      for (int mi = 0; mi < 4; ++mi)
#pragma unroll
        for (int ni = 0; ni < 4; ++ni)
          acc[mi][ni] = __builtin_amdgcn_mfma_f32_16x16x32_bf16(af[mi], bb[ni], acc[mi][ni], 0, 0, 0);
    }
  };

  const int nk = kcK >> 6;
  STAGE(0, 0);
  for (int kt = 0; kt < nk - 1; ++kt) {
    STAGE(kt + 1, (kt + 1) & 1);
    asm volatile("s_waitcnt vmcnt(10)" ::: "memory");
    __builtin_amdgcn_s_barrier();
    __builtin_amdgcn_sched_barrier(0);
    COMPUTE(kt & 1);
    asm volatile("s_waitcnt lgkmcnt(0)" ::: "memory");
    __builtin_amdgcn_s_barrier();
  }
  asm volatile("s_waitcnt vmcnt(0)" ::: "memory");
  __builtin_amdgcn_s_barrier();
  __builtin_amdgcn_sched_barrier(0);
  COMPUTE((nk - 1) & 1);

  float* oF = OUTF ? (g.oF + (long)kc * g.pstride) : (float*)nullptr;
  short* oB = OUTB ? (g.oB + (long)kc * g.pstride) : (short*)nullptr;
#pragma unroll
  for (int mi = 0; mi < 4; ++mi) {
#pragma unroll
    for (int ni = 0; ni < 4; ++ni) {
      const int n = bn0 + (ni << 4) + fc;
      float bv = 0.f;
      if (HASBIAS) bv = g.bias[n];
#pragma unroll
      for (int r = 0; r < 4; ++r) {
        const int m = wr + (mi << 4) + (fh << 2) + r;
        float v = acc[mi][ni][r] + bv;
        if (HASCI) v += bf2f(g.Ci[(long)m * g.ldci + n]);
        if (RELU) v = fmaxf(v, 0.f);
        if (OUTF) oF[(long)m * g.ldoF + n] = v;
        if (OUTB) oB[(long)m * g.ldoB + n] = f2bf(v);
      }
    }
  }
}

// ---------------------------------------------------------------------------
// throughput GEMM for batched precomputes (r2-proven): 128x128, BK=64.
// ---------------------------------------------------------------------------
template<int HASBIAS, int HASCI, int RELU, int OUTF, int OUTB>
__global__ __launch_bounds__(256) void gemm_bt(GArg g0, GArg g1, int kcK) {
  const int gemm = blockIdx.z & 1;
  const GArg g = gemm ? g1 : g0;
  const short* __restrict__ Ag = g.A;
  const short* __restrict__ Bg = g.Bt;
  __shared__ __align__(16) short As[2][8192];
  __shared__ __align__(16) short Bs[2][8192];
  const int tid = threadIdx.x;
  const int w = tid >> 6, l = tid & 63;
  const int bm0 = blockIdx.y << 7, bn0 = blockIdx.x << 7;
  const int fc = l & 15, fh = l >> 4;
  const int wr = (w >> 1) << 6, wc = (w & 1) << 6;
  const int rx = fc & 7;
  const int srccol = ((l & 7) ^ ((l >> 3) & 7)) << 3;
  long aoff[4], boff[4];
#pragma unroll
  for (int i = 0; i < 4; ++i) {
    const int row = (((i << 2) + w) << 3) + (l >> 3);
    aoff[i] = (long)(bm0 + row) * g.lda + srccol;
    boff[i] = (long)(bn0 + row) * g.ldb + srccol;
  }
  f32x4 acc[4][4];
#pragma unroll
  for (int i = 0; i < 4; ++i)
#pragma unroll
    for (int j = 0; j < 4; ++j) acc[i][j] = f32x4{0.f, 0.f, 0.f, 0.f};

  auto STAGE = [&](int kt, int buf) {
#pragma unroll
    for (int i = 0; i < 4; ++i) {
      const int ib = ((i << 2) + w) << 10;
      __builtin_amdgcn_global_load_lds(
          (const __attribute__((address_space(1))) void*)(Ag + aoff[i] + (kt << 6)),
          (__attribute__((address_space(3))) void*)((char*)&As[buf][0] + ib), 16, 0, 0);
      __builtin_amdgcn_global_load_lds(
          (const __attribute__((address_space(1))) void*)(Bg + boff[i] + (kt << 6)),
          (__attribute__((address_space(3))) void*)((char*)&Bs[buf][0] + ib), 16, 0, 0);
    }
  };
  auto COMPUTE = [&](int buf) {
#pragma unroll
    for (int kk = 0; kk < 2; ++kk) {
      bf16x8 af[4], bb[4];
#pragma unroll
      for (int mi = 0; mi < 4; ++mi)
        af[mi] = *(const bf16x8*)&As[buf][(wr + (mi << 4) + fc) * 64 + ((((kk << 2) + fh) ^ rx) << 3)];
#pragma unroll
      for (int ni = 0; ni < 4; ++ni)
        bb[ni] = *(const bf16x8*)&Bs[buf][(wc + (ni << 4) + fc) * 64 + ((((kk << 2) + fh) ^ rx) << 3)];
#pragma unroll
      for (int mi = 0; mi < 4; ++mi)
#pragma unroll
        for (int ni = 0; ni < 4; ++ni)
          acc[mi][ni] = __builtin_amdgcn_mfma_f32_16x16x32_bf16(af[mi], bb[ni], acc[mi][ni], 0, 0, 0);
    }
  };

  const int nk = kcK >> 6;
  STAGE(0, 0);
  for (int kt = 0; kt < nk - 1; ++kt) {
    STAGE(kt + 1, (kt + 1) & 1);
    asm volatile("s_waitcnt vmcnt(8)" ::: "memory");
    __builtin_amdgcn_s_barrier();
    __builtin_amdgcn_sched_barrier(0);
    COMPUTE(kt & 1);
    asm volatile("s_waitcnt lgkmcnt(0)" ::: "memory");
    __builtin_amdgcn_s_barrier();
  }
  asm volatile("s_waitcnt vmcnt(0)" ::: "memory");
  __builtin_amdgcn_s_barrier();
  __builtin_amdgcn_sched_barrier(0);
  COMPUTE((nk - 1) & 1);

#pragma unroll
  for (int mi = 0; mi < 4; ++mi) {
#pragma unroll
    for (int ni = 0; ni < 4; ++ni) {
      const int n = bn0 + wc + (ni << 4) + fc;
      float bv = 0.f;
      if (HASBIAS) bv = g.bias[n];
#pragma unroll
      for (int r = 0; r < 4; ++r) {
        const int m = bm0 + wr + (mi << 4) + (fh << 2) + r;
        float v = acc[mi][ni][r] + bv;
        if (HASCI) v += bf2f(g.Ci[(long)m * g.ldci + n]);
        if (RELU) v = fmaxf(v, 0.f);
        if (OUTF) g.oF[(long)m * g.ldoF + n] = v;
        if (OUTB) g.oB[(long)m * g.ldoB + n] = f2bf(v);
      }
    }
  }
}

// ---------------------------------------------------------------------------
// gi+gh+GRU fused (r7 EXACT, proven at 6.57ms).  Gate-permuted weights:
// row' = u*48 + g*16 + jlo.  Tile 64x96, wave 32x48, dual acc (48 VGPR),
// grid dim3(64,4), LDS 80KB, vmcnt(10).  h ping-pong in/out.
// ---------------------------------------------------------------------------
__global__ __launch_bounds__(256) void gigh_gru(
    const short* __restrict__ sa, const short* __restrict__ hb_in,
    const short* __restrict__ Wih, const short* __restrict__ Whh,
    const float* __restrict__ b_ih, const float* __restrict__ b_hh,
    const float* __restrict__ hold, float* __restrict__ hnew,
    short* __restrict__ hb_out) {
  __shared__ __align__(16) short AsS[2][4096];
  __shared__ __align__(16) short AsH[2][4096];
  __shared__ __align__(16) short BsI[2][6144];
  __shared__ __align__(16) short BsH[2][6144];
  const int tid = threadIdx.x;
  const int w = tid >> 6, l = tid & 63;
  const int bm0 = blockIdx.y << 6;
  const int bn0 = blockIdx.x * 96;
  const int fc = l & 15, fh = l >> 4;
  const int wr = (w >> 1) << 5;
  const int wn = (w & 1) * 48;
  const int rx = fc & 7;
  const int srccol = ((l & 7) ^ ((l >> 3) & 7)) << 3;

  long aoff[2], boff[3];
#pragma unroll
  for (int i = 0; i < 2; ++i) {
    const int row = (((i << 2) + w) << 3) + (l >> 3);
    aoff[i] = (long)(bm0 + row) * Hsz + srccol;
  }
#pragma unroll
  for (int i = 0; i < 3; ++i) {
    const int row = (((i << 2) + w) << 3) + (l >> 3);
    boff[i] = (long)(bn0 + row) * Hsz + srccol;
  }

  f32x4 acc_i[2][3], acc_h[2][3];
#pragma unroll
  for (int i = 0; i < 2; ++i)
#pragma unroll
    for (int j = 0; j < 3; ++j) { acc_i[i][j] = f32x4{0.f,0.f,0.f,0.f}; acc_h[i][j] = f32x4{0.f,0.f,0.f,0.f}; }

  auto STAGE = [&](int kt, int buf) {
#pragma unroll
    for (int i = 0; i < 2; ++i) {
      const int ib = ((i << 2) + w) << 10;
      __builtin_amdgcn_global_load_lds(
          (const __attribute__((address_space(1))) void*)(sa + aoff[i] + (kt << 6)),
          (__attribute__((address_space(3))) void*)((char*)&AsS[0][0] + (buf << 13) + ib), 16, 0, 0);
      __builtin_amdgcn_global_load_lds(
          (const __attribute__((address_space(1))) void*)(hb_in + aoff[i] + (kt << 6)),
          (__attribute__((address_space(3))) void*)((char*)&AsH[0][0] + (buf << 13) + ib), 16, 0, 0);
    }
#pragma unroll
    for (int i = 0; i < 3; ++i) {
      const int ib = ((i << 2) + w) << 10;
      __builtin_amdgcn_global_load_lds(
          (const __attribute__((address_space(1))) void*)(Wih + boff[i] + (kt << 6)),
          (__attribute__((address_space(3))) void*)((char*)&BsI[0][0] + buf * 12288 + ib), 16, 0, 0);
      __builtin_amdgcn_global_load_lds(
          (const __attribute__((address_space(1))) void*)(Whh + boff[i] + (kt << 6)),
          (__attribute__((address_space(3))) void*)((char*)&BsH[0][0] + buf * 12288 + ib), 16, 0, 0);
    }
  };
  auto COMPUTE = [&](int buf) {
#pragma unroll
    for (int kk = 0; kk < 2; ++kk) {
      const int sw = (((kk << 2) + fh) ^ rx) << 3;
      bf16x8 as_[2], ah_[2], bi_[3], bh_[3];
#pragma unroll
      for (int mi = 0; mi < 2; ++mi) {
        as_[mi] = *(const bf16x8*)&AsS[buf][(wr + (mi << 4) + fc) * 64 + sw];
        ah_[mi] = *(const bf16x8*)&AsH[buf][(wr + (mi << 4) + fc) * 64 + sw];
      }
#pragma unroll
      for (int ni = 0; ni < 3; ++ni) {
        bi_[ni] = *(const bf16x8*)&BsI[buf][(wn + (ni << 4) + fc) * 64 + sw];
        bh_[ni] = *(const bf16x8*)&BsH[buf][(wn + (ni << 4) + fc) * 64 + sw];
      }
#pragma unroll
      for (int mi = 0; mi < 2; ++mi)
#pragma unroll
        for (int ni = 0; ni < 3; ++ni) {
          acc_i[mi][ni] = __builtin_amdgcn_mfma_f32_16x16x32_bf16(as_[mi], bi_[ni], acc_i[mi][ni], 0, 0, 0);
          acc_h[mi][ni] = __builtin_amdgcn_mfma_f32_16x16x32_bf16(ah_[mi], bh_[ni], acc_h[mi][ni], 0, 0, 0);
        }
    }
  };

  const int nk = Hsz >> 6;
  STAGE(0, 0);
  for (int kt = 0; kt < nk - 1; ++kt) {
    STAGE(kt + 1, (kt + 1) & 1);
    asm volatile("s_waitcnt vmcnt(10)" ::: "memory");
    __builtin_amdgcn_s_barrier();
    __builtin_amdgcn_sched_barrier(0);
    COMPUTE(kt & 1);
    asm volatile("s_waitcnt lgkmcnt(0)" ::: "memory");
    __builtin_amdgcn_s_barrier();
  }
  asm volatile("s_waitcnt vmcnt(0)" ::: "memory");
  __builtin_amdgcn_s_barrier();
  __builtin_amdgcn_sched_barrier(0);
  COMPUTE((nk - 1) & 1);

  const int j = (((int)blockIdx.x << 1) + (w & 1)) * 16 + fc;
  const float bir = b_ih[j],            bhr = b_hh[j];
  const float biz = b_ih[Hsz + j],      bhz = b_hh[Hsz + j];
  const float bin = b_ih[2 * Hsz + j],  bhn = b_hh[2 * Hsz + j];
#pragma unroll
  for (int mi = 0; mi < 2; ++mi) {
#pragma unroll
    for (int r = 0; r < 4; ++r) {
      const int m = bm0 + wr + (mi << 4) + (fh << 2) + r;
      const float ir = acc_i[mi][0][r] + bir, hr = acc_h[mi][0][r] + bhr;
      const float iz = acc_i[mi][1][r] + biz, hz = acc_h[mi][1][r] + bhz;
      const float in_ = acc_i[mi][2][r] + bin, hn = acc_h[mi][2][r] + bhn;
      const float rg = 1.f / (1.f + expf(-(ir + hr)));
      const float zg = 1.f / (1.f + expf(-(iz + hz)));
      const float ng = tanhf(in_ + rg * hn);
      const float hv = (1.f - zg) * ng + zg * hold[(long)m * (Tsz * Hsz) + j];
      hnew[(long)m * (Tsz * Hsz) + j] = hv;
      hb_out[m * Hsz + j] = f2bf(hv);
    }
  }
}

// ---------------------------------------------------------------------------
// prior/post GEMM + fused rsample (r6 kernel).  Bt column-interleaved:
// row' = (j>>4)*32 + is_lv*16 + (j&15).  z=0: prior, z=1: posterior (s_b).
// Grid dim3(8, 2, 2), K=2048.
// ---------------------------------------------------------------------------
__global__ __launch_bounds__(256) void gemm_sample2(
    const short* __restrict__ A0, const short* __restrict__ A1,
    const short* __restrict__ B0, const short* __restrict__ B1,
    const float* __restrict__ bi0, const float* __restrict__ bi1,
    const float* __restrict__ n0, const float* __restrict__ n1,
    float* __restrict__ out, short* __restrict__ sb, int t) {
  const int z = blockIdx.z;
  const short* __restrict__ A = z ? A1 : A0;
  const short* __restrict__ Bt = z ? B1 : B0;
  const float* __restrict__ bias = z ? bi1 : bi0;
  const float* __restrict__ noise = z ? n1 : n0;
  const long oS = z ? OUT_QS : OUT_PS, oM = z ? OUT_QM : OUT_PM, oLV = z ? OUT_QLV : OUT_PLV;

  __shared__ __align__(16) short As[2][8192];
  __shared__ __align__(16) short Bs[2][8192];
  const int tid = threadIdx.x;
  const int w = tid >> 6, l = tid & 63;
  const int bm0 = blockIdx.y << 7, bn0 = blockIdx.x << 7;
  const int fc = l & 15, fh = l >> 4;
  const int wr = (w >> 1) << 6, wc = (w & 1) << 6;
  const int rx = fc & 7;
  const int srccol = ((l & 7) ^ ((l >> 3) & 7)) << 3;
  long aoff[4], boff[4];
#pragma unroll
  for (int i = 0; i < 4; ++i) {
    const int row = (((i << 2) + w) << 3) + (l >> 3);
    aoff[i] = (long)(bm0 + row) * Hsz + srccol;
    boff[i] = (long)(bn0 + row) * Hsz + srccol;
  }
  f32x4 acc[4][4];
#pragma unroll
  for (int i = 0; i < 4; ++i)
#pragma unroll
    for (int j = 0; j < 4; ++j) acc[i][j] = f32x4{0.f, 0.f, 0.f, 0.f};

  auto STAGE = [&](int kt, int buf) {
#pragma unroll
    for (int i = 0; i < 4; ++i) {
      const int ib = ((i << 2) + w) << 10;
      __builtin_amdgcn_global_load_lds(
          (const __attribute__((address_space(1))) void*)(A + aoff[i] + (kt << 6)),
          (__attribute__((address_space(3))) void*)((char*)&As[buf][0] + ib), 16, 0, 0);
      __builtin_amdgcn_global_load_lds(
          (const __attribute__((address_space(1))) void*)(Bt + boff[i] + (kt << 6)),
          (__attribute__((address_space(3))) void*)((char*)&Bs[buf][0] + ib), 16, 0, 0);
    }
  };
  auto COMPUTE = [&](int buf) {
#pragma unroll
    for (int kk = 0; kk < 2; ++kk) {
      bf16x8 af[4], bb[4];
#pragma unroll
      for (int mi = 0; mi < 4; ++mi)
        af[mi] = *(const bf16x8*)&As[buf][(wr + (mi << 4) + fc) * 64 + ((((kk << 2) + fh) ^ rx) << 3)];
#pragma unroll
      for (int ni = 0; ni < 4; ++ni)
        bb[ni] = *(const bf16x8*)&Bs[buf][(wc + (ni << 4) + fc) * 64 + ((((kk << 2) + fh) ^ rx) << 3)];
#pragma unroll
      for (int mi = 0; mi < 4; ++mi)
#pragma unroll
        for (int ni = 0; ni < 4; ++ni)
          acc[mi][ni] = __builtin_amdgcn_mfma_f32_16x16x32_bf16(af[mi], bb[ni], acc[mi][ni], 0, 0, 0);
    }
  };

  const int nk = Hsz >> 6;
  STAGE(0, 0);
  for (int kt = 0; kt < nk - 1; ++kt) {
    STAGE(kt + 1, (kt + 1) & 1);
    asm volatile("s_waitcnt vmcnt(8)" ::: "memory");
    __builtin_amdgcn_s_barrier();
    __builtin_amdgcn_sched_barrier(0);
    COMPUTE(kt & 1);
    asm volatile("s_waitcnt lgkmcnt(0)" ::: "memory");
    __builtin_amdgcn_s_barrier();
  }
  asm volatile("s_waitcnt vmcnt(0)" ::: "memory");
  __builtin_amdgcn_s_barrier();
  __builtin_amdgcn_sched_barrier(0);
  COMPUTE((nk - 1) & 1);

#pragma unroll
  for (int mi = 0; mi < 4; ++mi) {
#pragma unroll
    for (int nh = 0; nh < 2; ++nh) {
      const int ni = nh << 1;
      const int j = (((bn0 + wc + (ni << 4)) >> 5) << 4) + fc;
      const float bm = bias[j], blv = bias[512 + j];
#pragma unroll
      for (int r = 0; r < 4; ++r) {
        const int b = bm0 + wr + (mi << 4) + (fh << 2) + r;
        const float mv = acc[mi][ni][r] + bm;
        const float lv = acc[mi][ni + 1][r] + blv;
        const long noff = ((long)b * TM1 + t) * Ssz + j;
        const float sv = mv + (1.f + expf(lv)) * noise[noff];
        out[oS + (long)b * (Tsz * Ssz) + (long)(t + 1) * Ssz + j] = sv;
        out[oM + noff] = mv;
        out[oLV + noff] = lv;
        if (z) sb[b * Ssz + j] = f2bf(sv);
      }
    }
  }
}

// ---------------------------------------------------------------------------
// small kernels
// ---------------------------------------------------------------------------
__global__ void conv_f2b(const float* __restrict__ src, short* __restrict__ dst, long n) {
  long i = ((long)blockIdx.x * 256 + threadIdx.x) * 4;
  const long stride = (long)gridDim.x * 1024;
  for (; i < n; i += stride) {
    float4 v = *(const float4*)(src + i);
    s16x4 o;
    o[0] = f2bf(v.x); o[1] = f2bf(v.y); o[2] = f2bf(v.z); o[3] = f2bf(v.w);
    *(s16x4*)(dst + i) = o;
  }
}

// gate-permuting fp32->bf16 row copy for W_ih/W_hh [6144,2048]
__global__ void conv_perm48(const float* __restrict__ src, short* __restrict__ dst) {
  const long e = ((long)blockIdx.x * 256 + threadIdx.x) * 4;
  const int np = (int)(e >> 11), col = (int)(e & 2047);
  const int u = np / 48, rem = np - u * 48;
  const int g = rem >> 4, jlo = rem & 15;
  const long srow = ((long)g << 11) + u * 16 + jlo;
  float4 v = *(const float4*)&src[srow * 2048 + col];
  s16x4 o;
  o[0] = f2bf(v.x); o[1] = f2bf(v.y); o[2] = f2bf(v.z); o[3] = f2bf(v.w);
  *(s16x4*)&dst[e] = o;
}

template<int PERM>
__global__ void transp(const float* __restrict__ src, short* __restrict__ dst,
                       int srcld, int k0, int K, int N) {
  __shared__ float t[32][33];
  const int tx = threadIdx.x, ty = threadIdx.y;
  const int kb = blockIdx.y << 5, nb = blockIdx.x << 5;
#pragma unroll
  for (int i = ty; i < 32; i += 8)
    t[i][tx] = src[(long)(k0 + kb + i) * srcld + nb + tx];
  __syncthreads();
#pragma unroll
  for (int i = ty; i < 32; i += 8) {
    int n = nb + i, drow = n;
    if (PERM) { const int j = n & 511, lvb = n >> 9; drow = ((j >> 4) << 5) | (lvb << 4) | (j & 15); }
    dst[(long)drow * K + kb + tx] = f2bf(t[tx][i]);
  }
}

__global__ void init_kernel(const float* __restrict__ ph, const float* __restrict__ ps,
                            float* __restrict__ out, short* __restrict__ hb, short* __restrict__ sb) {
  const int idx = blockIdx.x * 256 + threadIdx.x;
  const int b = idx >> 11, n = idx & 2047;
  const float h = ph[idx];
  out[(long)b * (Tsz * Hsz) + n] = h;
  hb[idx] = f2bf(h);
  if (n < Ssz) {
    const int sidx = b * Ssz + n;
    const float s = ps[sidx];
    out[OUT_PS + (long)b * (Tsz * Ssz) + n] = s;
    out[OUT_QS + (long)b * (Tsz * Ssz) + n] = s;
    sb[sidx] = f2bf(s);
  }
}

static GArg mk(const short* A, int lda, const short* Bt, int ldb, const float* bias,
               const short* Ci, long ldci, float* oF, int ldoF, long pstride,
               short* oB, int ldoB) {
  GArg g; g.A = A; g.Bt = Bt; g.bias = bias; g.Ci = Ci; g.ldci = ldci;
  g.oF = oF; g.oB = oB; g.lda = lda; g.ldb = ldb; g.ldoF = ldoF; g.ldoB = ldoB;
  g.pstride = pstride;
  return g;
}

extern "C" void kernel_launch(void* const* d_in, const int* in_sizes, int n_in,
                              void* d_out, int out_size, void* d_ws, size_t ws_size,
                              hipStream_t stream) {
  const float* prev_hidden = (const float*)d_in[0];
  const float* prev_state  = (const float*)d_in[1];
  const float* actions     = (const float*)d_in[2];
  const float* obs         = (const float*)d_in[3];
  const float* prior_noise = (const float*)d_in[4];
  const float* post_noise  = (const float*)d_in[5];
  const float* W_sa = (const float*)d_in[6];
  const float* b_sa = (const float*)d_in[7];
  const float* W_ih = (const float*)d_in[8];
  const float* W_hh = (const float*)d_in[9];
  const float* b_ih = (const float*)d_in[10];
  const float* b_hh = (const float*)d_in[11];
  const float* W_ha = (const float*)d_in[12];
  const float* b_ha = (const float*)d_in[13];
  const float* W_prior = (const float*)d_in[14];
  const float* b_prior = (const float*)d_in[15];
  const float* W_ho = (const float*)d_in[16];
  const float* b_ho = (const float*)d_in[17];
  const float* W_post = (const float*)d_in[18];
  const float* b_post = (const float*)d_in[19];
  float* out = (float*)d_out;

  char* p = (char*)d_ws;
  auto alloc = [&](size_t bytes) { char* r = p; p += (bytes + 255) & ~(size_t)255; return r; };
  short* Wih_p   = (short*)alloc(3L * Hsz * Hsz * 2);      // gate-permuted
  short* Whh_p   = (short*)alloc(3L * Hsz * Hsz * 2);
  short* Wt_sa_s = (short*)alloc((long)Hsz * Ssz * 2);
  short* Wt_sa_a = (short*)alloc((long)Hsz * Asz * 2);
  short* Wt_ha_h = (short*)alloc((long)Hsz * Hsz * 2);
  short* Wt_ha_a = (short*)alloc((long)Hsz * Asz * 2);
  short* Wt_ho_h = (short*)alloc((long)Hsz * Hsz * 2);
  short* Wt_ho_o = (short*)alloc((long)Hsz * Esz * 2);
  short* Wt_pr   = (short*)alloc(2L * Ssz * Hsz * 2);      // mean/lv interleaved
  short* Wt_po   = (short*)alloc(2L * Ssz * Hsz * 2);
  short* obs_b   = (short*)alloc((long)Bsz * Tsz * Esz * 2);
  short* act_b   = (short*)alloc((long)Bsz * Tsz * Asz * 2);
  short* a_pre   = (short*)alloc((long)Bsz * Tsz * Hsz * 2);
  short* ha_a    = (short*)alloc((long)Bsz * Tsz * Hsz * 2);
  short* ho_o    = (short*)alloc((long)Bsz * Tsz * Hsz * 2);
  short* s_b     = (short*)alloc((long)Bsz * Ssz * 2);
  short* h_b1    = (short*)alloc((long)Bsz * Hsz * 2);     // h ping-pong
  short* h_b2    = (short*)alloc((long)Bsz * Hsz * 2);
  short* sa_b    = (short*)alloc((long)Bsz * Hsz * 2);
  short* ha_b    = (short*)alloc((long)Bsz * Hsz * 2);
  short* ho_b    = (short*)alloc((long)Bsz * Hsz * 2);
  (void)ws_size; (void)in_sizes; (void)n_in; (void)out_size;

  // ---- setup ----------------------------------------------------------------
  conv_f2b<<<4096, 256, 0, stream>>>(obs,  obs_b, (long)Bsz * Tsz * Esz);
  conv_f2b<<<1024, 256, 0, stream>>>(actions, act_b, (long)Bsz * Tsz * Asz);
  conv_perm48<<<12288, 256, 0, stream>>>(W_ih, Wih_p);
  conv_perm48<<<12288, 256, 0, stream>>>(W_hh, Whh_p);

  dim3 tb(32, 8);
  transp<0><<<dim3(Hsz / 32, Ssz / 32), tb, 0, stream>>>(W_sa, Wt_sa_s, Hsz, 0,   Ssz, Hsz);
  transp<0><<<dim3(Hsz / 32, Asz / 32), tb, 0, stream>>>(W_sa, Wt_sa_a, Hsz, Ssz, Asz, Hsz);
  transp<0><<<dim3(Hsz / 32, Hsz / 32), tb, 0, stream>>>(W_ha, Wt_ha_h, Hsz, 0,   Hsz, Hsz);
  transp<0><<<dim3(Hsz / 32, Asz / 32), tb, 0, stream>>>(W_ha, Wt_ha_a, Hsz, Hsz, Asz, Hsz);
  transp<0><<<dim3(Hsz / 32, Hsz / 32), tb, 0, stream>>>(W_ho, Wt_ho_h, Hsz, 0,   Hsz, Hsz);
  transp<0><<<dim3(Hsz / 32, Esz / 32), tb, 0, stream>>>(W_ho, Wt_ho_o, Hsz, Hsz, Esz, Hsz);
  transp<1><<<dim3(2 * Ssz / 32, Hsz / 32), tb, 0, stream>>>(W_prior, Wt_pr, 2 * Ssz, 0, Hsz, 2 * Ssz);
  transp<1><<<dim3(2 * Ssz / 32, Hsz / 32), tb, 0, stream>>>(W_post,  Wt_po, 2 * Ssz, 0, Hsz, 2 * Ssz);

  init_kernel<<<2048, 256, 0, stream>>>(prev_hidden, prev_state, out, h_b1, s_b);

  // t-independent precomputes
  {
    GArg g0 = mk(act_b, Asz, Wt_sa_a, Asz, b_sa, nullptr, 0, nullptr, 0, 0, a_pre, Hsz);
    GArg g1 = mk(act_b, Asz, Wt_ha_a, Asz, b_ha, nullptr, 0, nullptr, 0, 0, ha_a, Hsz);
    gemm_bt<1, 0, 0, 0, 1><<<dim3(Hsz / 128, (Bsz * Tsz) / 128, 2), 256, 0, stream>>>(g0, g1, Asz);
  }
  {
    GArg g0 = mk(obs_b, Esz, Wt_ho_o, Esz, b_ho, nullptr, 0, nullptr, 0, 0, ho_o, Hsz);
    gemm_bt<1, 0, 0, 0, 1><<<dim3(Hsz / 128, (Bsz * Tsz) / 128, 1), 256, 0, stream>>>(g0, g0, Esz);
  }

  // ---- sequential scan: 4 dispatches / step ---------------------------------
  const long ldPre = (long)Tsz * Hsz;
  for (int t = 0; t < TM1; ++t) {
    short* hp = (t & 1) ? h_b2 : h_b1;    // h_t
    short* hn = (t & 1) ? h_b1 : h_b2;    // h_{t+1}
    // 1) sa = relu(s @ Wsa_s^T + a_pre[t])          [256,2048] K=512, 32 blks
    {
      GArg g0 = mk(s_b, Ssz, Wt_sa_s, Ssz, nullptr, a_pre + (long)t * Hsz, ldPre,
                   nullptr, 0, 0, sa_b, Hsz);
      gemm_n64<0, 1, 1, 0, 1><<<dim3(32, 1, 1), 256, 0, stream>>>(g0, g0, 0, Ssz);
    }
    // 2) gi+gh GEMMs + GRU fused -> h               [256,6144] K=2048, 256 blks
    gigh_gru<<<dim3(64, 4, 1), 256, 0, stream>>>(
        sa_b, hp, Wih_p, Whh_p, b_ih, b_hh,
        out + (long)t * Hsz, out + (long)(t + 1) * Hsz, hn);
    // 3) ha/ho unsplit + Ci + ReLU                  [256,2048] K=2048, 64 blks
    {
      GArg g0 = mk(hn, Hsz, Wt_ha_h, Hsz, nullptr, ha_a + (long)t * Hsz, ldPre,
                   nullptr, 0, 0, ha_b, Hsz);
      GArg g1 = mk(hn, Hsz, Wt_ho_h, Hsz, nullptr, ho_o + (long)t * Hsz, ldPre,
                   nullptr, 0, 0, ho_b, Hsz);
      gemm_n64<0, 1, 1, 0, 1><<<dim3(32, 1, 2), 256, 0, stream>>>(g0, g1, 1, Hsz);
    }
    // 4) prior/post GEMM + fused rsample            [256,1024] K=2048, 32 blks
    gemm_sample2<<<dim3(8, 2, 2), 256, 0, stream>>>(
        ha_b, ho_b, Wt_pr, Wt_po, b_prior, b_post,
        prior_noise, post_noise, out, s_b, t);
  }
}

// Round 10
// 7419.075 us; speedup vs baseline: 1.4287x; 1.4287x over previous
//
#include <hip/hip_runtime.h>

// ============================================================================
// RSSM (DynamicsModel) on MI355X — round 10.
// Model from ledger: kernel time ~ bytes-per-block / per-CU stream BW, plus
// ~11us/dispatch.  r9's fused kernels failed because they had FEW BIG blocks
// (32-64 x 1-1.25MB).  This round fuses with MANY SMALL blocks:
//   1. sa (r7 gemm_bt exact)              2. gigh_gru (r7 exact)
//   3. haho64: 64x64 tiles, 256 blocks, fused Ci+ReLU  (kills reduce)
//   4. prpo_sample64: 64x64 tiles, 128 blocks, fused rsample (kills sample)
// 4 dispatches/step, each <=0.5MB/block.
// ============================================================================

typedef __attribute__((ext_vector_type(8))) short bf16x8;
typedef __attribute__((ext_vector_type(4))) float f32x4;
typedef __attribute__((ext_vector_type(4))) short s16x4;

#define DEVI static __device__ __forceinline__

DEVI float bf2f(short s) { union { float f; unsigned u; } v; v.u = ((unsigned)(unsigned short)s) << 16; return v.f; }
DEVI short f2bf(float f) {
  union { float f; unsigned u; } v; v.f = f;
  unsigned r = v.u + 0x7FFFu + ((v.u >> 16) & 1u);   // RNE
  return (short)(r >> 16);
}

#define Bsz 256
#define Tsz 64
#define Hsz 2048
#define Ssz 512
#define Asz 64
#define Esz 2048
#define TM1 63

#define OUT_PS  33554432L
#define OUT_QS  41943040L
#define OUT_PM  50331648L
#define OUT_PLV 58589184L
#define OUT_QM  66846720L
#define OUT_QLV 75104256L

struct GArg {
  const short* A; const short* Bt; const float* bias; const short* Ci;
  float* oF; short* oB;
  int lda, ldb, ldoF, ldoB; long ldci, pstride;
};

// ---------------------------------------------------------------------------
// throughput GEMM (r2-proven): 128x128, BK=64, dbuf, swizzle, vmcnt(8).
// Used for: precomputes (z-dual) and the per-step sa GEMM.
// ---------------------------------------------------------------------------
template<int HASBIAS, int HASCI, int RELU, int OUTF, int OUTB>
__global__ __launch_bounds__(256) void gemm_bt(GArg g0, GArg g1, int kcK) {
  const int gemm = blockIdx.z & 1;
  const GArg g = gemm ? g1 : g0;
  const short* __restrict__ Ag = g.A;
  const short* __restrict__ Bg = g.Bt;
  __shared__ __align__(16) short As[2][8192];
  __shared__ __align__(16) short Bs[2][8192];
  const int tid = threadIdx.x;
  const int w = tid >> 6, l = tid & 63;
  const int bm0 = blockIdx.y << 7, bn0 = blockIdx.x << 7;
  const int fc = l & 15, fh = l >> 4;
  const int wr = (w >> 1) << 6, wc = (w & 1) << 6;
  const int rx = fc & 7;
  const int srccol = ((l & 7) ^ ((l >> 3) & 7)) << 3;
  long aoff[4], boff[4];
#pragma unroll
  for (int i = 0; i < 4; ++i) {
    const int row = (((i << 2) + w) << 3) + (l >> 3);
    aoff[i] = (long)(bm0 + row) * g.lda + srccol;
    boff[i] = (long)(bn0 + row) * g.ldb + srccol;
  }
  f32x4 acc[4][4];
#pragma unroll
  for (int i = 0; i < 4; ++i)
#pragma unroll
    for (int j = 0; j < 4; ++j) acc[i][j] = f32x4{0.f, 0.f, 0.f, 0.f};

  auto STAGE = [&](int kt, int buf) {
#pragma unroll
    for (int i = 0; i < 4; ++i) {
      const int ib = ((i << 2) + w) << 10;
      __builtin_amdgcn_global_load_lds(
          (const __attribute__((address_space(1))) void*)(Ag + aoff[i] + (kt << 6)),
          (__attribute__((address_space(3))) void*)((char*)&As[buf][0] + ib), 16, 0, 0);
      __builtin_amdgcn_global_load_lds(
          (const __attribute__((address_space(1))) void*)(Bg + boff[i] + (kt << 6)),
          (__attribute__((address_space(3))) void*)((char*)&Bs[buf][0] + ib), 16, 0, 0);
    }
  };
  auto COMPUTE = [&](int buf) {
#pragma unroll
    for (int kk = 0; kk < 2; ++kk) {
      bf16x8 af[4], bb[4];
#pragma unroll
      for (int mi = 0; mi < 4; ++mi)
        af[mi] = *(const bf16x8*)&As[buf][(wr + (mi << 4) + fc) * 64 + ((((kk << 2) + fh) ^ rx) << 3)];
#pragma unroll
      for (int ni = 0; ni < 4; ++ni)
        bb[ni] = *(const bf16x8*)&Bs[buf][(wc + (ni << 4) + fc) * 64 + ((((kk << 2) + fh) ^ rx) << 3)];
#pragma unroll
      for (int mi = 0; mi < 4; ++mi)
#pragma unroll
        for (int ni = 0; ni < 4; ++ni)
          acc[mi][ni] = __builtin_amdgcn_mfma_f32_16x16x32_bf16(af[mi], bb[ni], acc[mi][ni], 0, 0, 0);
    }
  };

  const int nk = kcK >> 6;
  STAGE(0, 0);
  for (int kt = 0; kt < nk - 1; ++kt) {
    STAGE(kt + 1, (kt + 1) & 1);
    asm volatile("s_waitcnt vmcnt(8)" ::: "memory");
    __builtin_amdgcn_s_barrier();
    __builtin_amdgcn_sched_barrier(0);
    COMPUTE(kt & 1);
    asm volatile("s_waitcnt lgkmcnt(0)" ::: "memory");
    __builtin_amdgcn_s_barrier();
  }
  asm volatile("s_waitcnt vmcnt(0)" ::: "memory");
  __builtin_amdgcn_s_barrier();
  __builtin_amdgcn_sched_barrier(0);
  COMPUTE((nk - 1) & 1);

#pragma unroll
  for (int mi = 0; mi < 4; ++mi) {
#pragma unroll
    for (int ni = 0; ni < 4; ++ni) {
      const int n = bn0 + wc + (ni << 4) + fc;
      float bv = 0.f;
      if (HASBIAS) bv = g.bias[n];
#pragma unroll
      for (int r = 0; r < 4; ++r) {
        const int m = bm0 + wr + (mi << 4) + (fh << 2) + r;
        float v = acc[mi][ni][r] + bv;
        if (HASCI) v += bf2f(g.Ci[(long)m * g.ldci + n]);
        if (RELU) v = fmaxf(v, 0.f);
        if (OUTF) g.oF[(long)m * g.ldoF + n] = v;
        if (OUTB) g.oB[(long)m * g.ldoB + n] = f2bf(v);
      }
    }
  }
}

// ---------------------------------------------------------------------------
// gi+gh+GRU fused (r7 EXACT, proven).  Gate-permuted weights:
// row' = u*48 + g*16 + jlo.  Tile 64x96, wave 32x48, grid dim3(64,4).
// ---------------------------------------------------------------------------
__global__ __launch_bounds__(256) void gigh_gru(
    const short* __restrict__ sa, const short* __restrict__ hb_in,
    const short* __restrict__ Wih, const short* __restrict__ Whh,
    const float* __restrict__ b_ih, const float* __restrict__ b_hh,
    const float* __restrict__ hold, float* __restrict__ hnew,
    short* __restrict__ hb_out) {
  __shared__ __align__(16) short AsS[2][4096];
  __shared__ __align__(16) short AsH[2][4096];
  __shared__ __align__(16) short BsI[2][6144];
  __shared__ __align__(16) short BsH[2][6144];
  const int tid = threadIdx.x;
  const int w = tid >> 6, l = tid & 63;
  const int bm0 = blockIdx.y << 6;
  const int bn0 = blockIdx.x * 96;
  const int fc = l & 15, fh = l >> 4;
  const int wr = (w >> 1) << 5;
  const int wn = (w & 1) * 48;
  const int rx = fc & 7;
  const int srccol = ((l & 7) ^ ((l >> 3) & 7)) << 3;

  long aoff[2], boff[3];
#pragma unroll
  for (int i = 0; i < 2; ++i) {
    const int row = (((i << 2) + w) << 3) + (l >> 3);
    aoff[i] = (long)(bm0 + row) * Hsz + srccol;
  }
#pragma unroll
  for (int i = 0; i < 3; ++i) {
    const int row = (((i << 2) + w) << 3) + (l >> 3);
    boff[i] = (long)(bn0 + row) * Hsz + srccol;
  }

  f32x4 acc_i[2][3], acc_h[2][3];
#pragma unroll
  for (int i = 0; i < 2; ++i)
#pragma unroll
    for (int j = 0; j < 3; ++j) { acc_i[i][j] = f32x4{0.f,0.f,0.f,0.f}; acc_h[i][j] = f32x4{0.f,0.f,0.f,0.f}; }

  auto STAGE = [&](int kt, int buf) {
#pragma unroll
    for (int i = 0; i < 2; ++i) {
      const int ib = ((i << 2) + w) << 10;
      __builtin_amdgcn_global_load_lds(
          (const __attribute__((address_space(1))) void*)(sa + aoff[i] + (kt << 6)),
          (__attribute__((address_space(3))) void*)((char*)&AsS[0][0] + (buf << 13) + ib), 16, 0, 0);
      __builtin_amdgcn_global_load_lds(
          (const __attribute__((address_space(1))) void*)(hb_in + aoff[i] + (kt << 6)),
          (__attribute__((address_space(3))) void*)((char*)&AsH[0][0] + (buf << 13) + ib), 16, 0, 0);
    }
#pragma unroll
    for (int i = 0; i < 3; ++i) {
      const int ib = ((i << 2) + w) << 10;
      __builtin_amdgcn_global_load_lds(
          (const __attribute__((address_space(1))) void*)(Wih + boff[i] + (kt << 6)),
          (__attribute__((address_space(3))) void*)((char*)&BsI[0][0] + buf * 12288 + ib), 16, 0, 0);
      __builtin_amdgcn_global_load_lds(
          (const __attribute__((address_space(1))) void*)(Whh + boff[i] + (kt << 6)),
          (__attribute__((address_space(3))) void*)((char*)&BsH[0][0] + buf * 12288 + ib), 16, 0, 0);
    }
  };
  auto COMPUTE = [&](int buf) {
#pragma unroll
    for (int kk = 0; kk < 2; ++kk) {
      const int sw = (((kk << 2) + fh) ^ rx) << 3;
      bf16x8 as_[2], ah_[2], bi_[3], bh_[3];
#pragma unroll
      for (int mi = 0; mi < 2; ++mi) {
        as_[mi] = *(const bf16x8*)&AsS[buf][(wr + (mi << 4) + fc) * 64 + sw];
        ah_[mi] = *(const bf16x8*)&AsH[buf][(wr + (mi << 4) + fc) * 64 + sw];
      }
#pragma unroll
      for (int ni = 0; ni < 3; ++ni) {
        bi_[ni] = *(const bf16x8*)&BsI[buf][(wn + (ni << 4) + fc) * 64 + sw];
        bh_[ni] = *(const bf16x8*)&BsH[buf][(wn + (ni << 4) + fc) * 64 + sw];
      }
#pragma unroll
      for (int mi = 0; mi < 2; ++mi)
#pragma unroll
        for (int ni = 0; ni < 3; ++ni) {
          acc_i[mi][ni] = __builtin_amdgcn_mfma_f32_16x16x32_bf16(as_[mi], bi_[ni], acc_i[mi][ni], 0, 0, 0);
          acc_h[mi][ni] = __builtin_amdgcn_mfma_f32_16x16x32_bf16(ah_[mi], bh_[ni], acc_h[mi][ni], 0, 0, 0);
        }
    }
  };

  const int nk = Hsz >> 6;
  STAGE(0, 0);
  for (int kt = 0; kt < nk - 1; ++kt) {
    STAGE(kt + 1, (kt + 1) & 1);
    asm volatile("s_waitcnt vmcnt(10)" ::: "memory");
    __builtin_amdgcn_s_barrier();
    __builtin_amdgcn_sched_barrier(0);
    COMPUTE(kt & 1);
    asm volatile("s_waitcnt lgkmcnt(0)" ::: "memory");
    __builtin_amdgcn_s_barrier();
  }
  asm volatile("s_waitcnt vmcnt(0)" ::: "memory");
  __builtin_amdgcn_s_barrier();
  __builtin_amdgcn_sched_barrier(0);
  COMPUTE((nk - 1) & 1);

  const int j = (((int)blockIdx.x << 1) + (w & 1)) * 16 + fc;
  const float bir = b_ih[j],            bhr = b_hh[j];
  const float biz = b_ih[Hsz + j],      bhz = b_hh[Hsz + j];
  const float bin = b_ih[2 * Hsz + j],  bhn = b_hh[2 * Hsz + j];
#pragma unroll
  for (int mi = 0; mi < 2; ++mi) {
#pragma unroll
    for (int r = 0; r < 4; ++r) {
      const int m = bm0 + wr + (mi << 4) + (fh << 2) + r;
      const float ir = acc_i[mi][0][r] + bir, hr = acc_h[mi][0][r] + bhr;
      const float iz = acc_i[mi][1][r] + biz, hz = acc_h[mi][1][r] + bhz;
      const float in_ = acc_i[mi][2][r] + bin, hn = acc_h[mi][2][r] + bhn;
      const float rg = 1.f / (1.f + expf(-(ir + hr)));
      const float zg = 1.f / (1.f + expf(-(iz + hz)));
      const float ng = tanhf(in_ + rg * hn);
      const float hv = (1.f - zg) * ng + zg * hold[(long)m * (Tsz * Hsz) + j];
      hnew[(long)m * (Tsz * Hsz) + j] = hv;
      hb_out[m * Hsz + j] = f2bf(hv);
    }
  }
}

// ---------------------------------------------------------------------------
// haho64: C = relu(A @ B^T + Ci) -> bf16.  64x64 tile, K=2048 unsplit,
// 4 waves (wave 32x32), LDS 32KB dbuf, vmcnt(4).  Grid dim3(32,4,2):
// x = n-block, y = m-block, z selects {ha, ho}.  0.5MB/block.
// ---------------------------------------------------------------------------
__global__ __launch_bounds__(256) void haho64(
    const short* __restrict__ A, const short* __restrict__ B0,
    const short* __restrict__ B1, const short* __restrict__ Ci0,
    const short* __restrict__ Ci1, long ldci,
    short* __restrict__ o0, short* __restrict__ o1) {
  const int z = blockIdx.z;
  const short* __restrict__ Bg = z ? B1 : B0;
  const short* __restrict__ Ci = z ? Ci1 : Ci0;
  short* __restrict__ o = z ? o1 : o0;
  __shared__ __align__(16) short As[2][4096];
  __shared__ __align__(16) short Bs[2][4096];
  const int tid = threadIdx.x;
  const int w = tid >> 6, l = tid & 63;
  const int bm0 = blockIdx.y << 6, bn0 = blockIdx.x << 6;
  const int fc = l & 15, fh = l >> 4;
  const int wr = (w >> 1) << 5, wc = (w & 1) << 5;
  const int rx = fc & 7;
  const int srccol = ((l & 7) ^ ((l >> 3) & 7)) << 3;

  long aoff[2], boff[2];
#pragma unroll
  for (int i = 0; i < 2; ++i) {
    const int row = (((i << 2) + w) << 3) + (l >> 3);    // 0..63
    aoff[i] = (long)(bm0 + row) * Hsz + srccol;
    boff[i] = (long)(bn0 + row) * Hsz + srccol;
  }

  f32x4 acc[2][2];
#pragma unroll
  for (int i = 0; i < 2; ++i)
#pragma unroll
    for (int j = 0; j < 2; ++j) acc[i][j] = f32x4{0.f, 0.f, 0.f, 0.f};

  auto STAGE = [&](int kt, int buf) {
#pragma unroll
    for (int i = 0; i < 2; ++i) {
      const int ib = ((i << 2) + w) << 10;
      __builtin_amdgcn_global_load_lds(
          (const __attribute__((address_space(1))) void*)(A + aoff[i] + (kt << 6)),
          (__attribute__((address_space(3))) void*)((char*)&As[buf][0] + ib), 16, 0, 0);
      __builtin_amdgcn_global_load_lds(
          (const __attribute__((address_space(1))) void*)(Bg + boff[i] + (kt << 6)),
          (__attribute__((address_space(3))) void*)((char*)&Bs[buf][0] + ib), 16, 0, 0);
    }
  };
  auto COMPUTE = [&](int buf) {
#pragma unroll
    for (int kk = 0; kk < 2; ++kk) {
      const int sw = (((kk << 2) + fh) ^ rx) << 3;
      bf16x8 af[2], bb[2];
#pragma unroll
      for (int mi = 0; mi < 2; ++mi)
        af[mi] = *(const bf16x8*)&As[buf][(wr + (mi << 4) + fc) * 64 + sw];
#pragma unroll
      for (int ni = 0; ni < 2; ++ni)
        bb[ni] = *(const bf16x8*)&Bs[buf][(wc + (ni << 4) + fc) * 64 + sw];
#pragma unroll
      for (int mi = 0; mi < 2; ++mi)
#pragma unroll
        for (int ni = 0; ni < 2; ++ni)
          acc[mi][ni] = __builtin_amdgcn_mfma_f32_16x16x32_bf16(af[mi], bb[ni], acc[mi][ni], 0, 0, 0);
    }
  };

  const int nk = Hsz >> 6;   // 32
  STAGE(0, 0);
  for (int kt = 0; kt < nk - 1; ++kt) {
    STAGE(kt + 1, (kt + 1) & 1);
    asm volatile("s_waitcnt vmcnt(4)" ::: "memory");
    __builtin_amdgcn_s_barrier();
    __builtin_amdgcn_sched_barrier(0);
    COMPUTE(kt & 1);
    asm volatile("s_waitcnt lgkmcnt(0)" ::: "memory");
    __builtin_amdgcn_s_barrier();
  }
  asm volatile("s_waitcnt vmcnt(0)" ::: "memory");
  __builtin_amdgcn_s_barrier();
  __builtin_amdgcn_sched_barrier(0);
  COMPUTE((nk - 1) & 1);

#pragma unroll
  for (int mi = 0; mi < 2; ++mi) {
#pragma unroll
    for (int ni = 0; ni < 2; ++ni) {
      const int n = bn0 + wc + (ni << 4) + fc;
#pragma unroll
      for (int r = 0; r < 4; ++r) {
        const int m = bm0 + wr + (mi << 4) + (fh << 2) + r;
        const float v = acc[mi][ni][r] + bf2f(Ci[(long)m * ldci + n]);
        o[(long)m * Hsz + n] = f2bf(fmaxf(v, 0.f));
      }
    }
  }
}

// ---------------------------------------------------------------------------
// prpo_sample64: (mean|logvar) GEMM + fused rsample.  B column-interleaved
// (row' = (j>>4)*32 + lv*16 + (j&15)) so ni=0 frag = mean, ni=1 = logvar of
// the same j within each wave.  64x64 tile, K=2048 unsplit.  Grid
// dim3(16,4,2): z=0 prior, z=1 posterior (also writes s_b).  0.5MB/block.
// ---------------------------------------------------------------------------
__global__ __launch_bounds__(256) void prpo_sample64(
    const short* __restrict__ A0, const short* __restrict__ A1,
    const short* __restrict__ B0, const short* __restrict__ B1,
    const float* __restrict__ bi0, const float* __restrict__ bi1,
    const float* __restrict__ n0, const float* __restrict__ n1,
    float* __restrict__ out, short* __restrict__ sb, int t) {
  const int z = blockIdx.z;
  const short* __restrict__ A = z ? A1 : A0;
  const short* __restrict__ Bg = z ? B1 : B0;
  const float* __restrict__ bias = z ? bi1 : bi0;
  const float* __restrict__ noise = z ? n1 : n0;
  const long oS = z ? OUT_QS : OUT_PS, oM = z ? OUT_QM : OUT_PM, oLV = z ? OUT_QLV : OUT_PLV;
  __shared__ __align__(16) short As[2][4096];
  __shared__ __align__(16) short Bs[2][4096];
  const int tid = threadIdx.x;
  const int w = tid >> 6, l = tid & 63;
  const int bm0 = blockIdx.y << 6, bn0 = blockIdx.x << 6;
  const int fc = l & 15, fh = l >> 4;
  const int wr = (w >> 1) << 5, wc = (w & 1) << 5;
  const int rx = fc & 7;
  const int srccol = ((l & 7) ^ ((l >> 3) & 7)) << 3;

  long aoff[2], boff[2];
#pragma unroll
  for (int i = 0; i < 2; ++i) {
    const int row = (((i << 2) + w) << 3) + (l >> 3);
    aoff[i] = (long)(bm0 + row) * Hsz + srccol;
    boff[i] = (long)(bn0 + row) * Hsz + srccol;
  }

  f32x4 acc[2][2];
#pragma unroll
  for (int i = 0; i < 2; ++i)
#pragma unroll
    for (int j = 0; j < 2; ++j) acc[i][j] = f32x4{0.f, 0.f, 0.f, 0.f};

  auto STAGE = [&](int kt, int buf) {
#pragma unroll
    for (int i = 0; i < 2; ++i) {
      const int ib = ((i << 2) + w) << 10;
      __builtin_amdgcn_global_load_lds(
          (const __attribute__((address_space(1))) void*)(A + aoff[i] + (kt << 6)),
          (__attribute__((address_space(3))) void*)((char*)&As[buf][0] + ib), 16, 0, 0);
      __builtin_amdgcn_global_load_lds(
          (const __attribute__((address_space(1))) void*)(Bg + boff[i] + (kt << 6)),
          (__attribute__((address_space(3))) void*)((char*)&Bs[buf][0] + ib), 16, 0, 0);
    }
  };
  auto COMPUTE = [&](int buf) {
#pragma unroll
    for (int kk = 0; kk < 2; ++kk) {
      const int sw = (((kk << 2) + fh) ^ rx) << 3;
      bf16x8 af[2], bb[2];
#pragma unroll
      for (int mi = 0; mi < 2; ++mi)
        af[mi] = *(const bf16x8*)&As[buf][(wr + (mi << 4) + fc) * 64 + sw];
#pragma unroll
      for (int ni = 0; ni < 2; ++ni)
        bb[ni] = *(const bf16x8*)&Bs[buf][(wc + (ni << 4) + fc) * 64 + sw];
#pragma unroll
      for (int mi = 0; mi < 2; ++mi)
#pragma unroll
        for (int ni = 0; ni < 2; ++ni)
          acc[mi][ni] = __builtin_amdgcn_mfma_f32_16x16x32_bf16(af[mi], bb[ni], acc[mi][ni], 0, 0, 0);
    }
  };

  const int nk = Hsz >> 6;
  STAGE(0, 0);
  for (int kt = 0; kt < nk - 1; ++kt) {
    STAGE(kt + 1, (kt + 1) & 1);
    asm volatile("s_waitcnt vmcnt(4)" ::: "memory");
    __builtin_amdgcn_s_barrier();
    __builtin_amdgcn_sched_barrier(0);
    COMPUTE(kt & 1);
    asm volatile("s_waitcnt lgkmcnt(0)" ::: "memory");
    __builtin_amdgcn_s_barrier();
  }
  asm volatile("s_waitcnt vmcnt(0)" ::: "memory");
  __builtin_amdgcn_s_barrier();
  __builtin_amdgcn_sched_barrier(0);
  COMPUTE((nk - 1) & 1);

  // pairing: ni=0 -> mean, ni=1 -> logvar, same state index j
  const int j = (((bn0 + wc) >> 5) << 4) + fc;   // [0,512)
  const float bm_ = bias[j], blv = bias[512 + j];
#pragma unroll
  for (int mi = 0; mi < 2; ++mi) {
#pragma unroll
    for (int r = 0; r < 4; ++r) {
      const int b = bm0 + wr + (mi << 4) + (fh << 2) + r;
      const float mv = acc[mi][0][r] + bm_;
      const float lv = acc[mi][1][r] + blv;
      const long noff = ((long)b * TM1 + t) * Ssz + j;
      const float sv = mv + (1.f + expf(lv)) * noise[noff];
      out[oS + (long)b * (Tsz * Ssz) + (long)(t + 1) * Ssz + j] = sv;
      out[oM + noff] = mv;
      out[oLV + noff] = lv;
      if (z) sb[b * Ssz + j] = f2bf(sv);
    }
  }
}

// ---------------------------------------------------------------------------
// small kernels
// ---------------------------------------------------------------------------
__global__ void conv_f2b(const float* __restrict__ src, short* __restrict__ dst, long n) {
  long i = ((long)blockIdx.x * 256 + threadIdx.x) * 4;
  const long stride = (long)gridDim.x * 1024;
  for (; i < n; i += stride) {
    float4 v = *(const float4*)(src + i);
    s16x4 o;
    o[0] = f2bf(v.x); o[1] = f2bf(v.y); o[2] = f2bf(v.z); o[3] = f2bf(v.w);
    *(s16x4*)(dst + i) = o;
  }
}

// gate-permuting fp32->bf16 row copy for W_ih/W_hh [6144,2048]
__global__ void conv_perm48(const float* __restrict__ src, short* __restrict__ dst) {
  const long e = ((long)blockIdx.x * 256 + threadIdx.x) * 4;
  const int np = (int)(e >> 11), col = (int)(e & 2047);
  const int u = np / 48, rem = np - u * 48;
  const int g = rem >> 4, jlo = rem & 15;
  const long srow = ((long)g << 11) + u * 16 + jlo;
  float4 v = *(const float4*)&src[srow * 2048 + col];
  s16x4 o;
  o[0] = f2bf(v.x); o[1] = f2bf(v.y); o[2] = f2bf(v.z); o[3] = f2bf(v.w);
  *(s16x4*)&dst[e] = o;
}

template<int PERM>
__global__ void transp(const float* __restrict__ src, short* __restrict__ dst,
                       int srcld, int k0, int K, int N) {
  __shared__ float t[32][33];
  const int tx = threadIdx.x, ty = threadIdx.y;
  const int kb = blockIdx.y << 5, nb = blockIdx.x << 5;
#pragma unroll
  for (int i = ty; i < 32; i += 8)
    t[i][tx] = src[(long)(k0 + kb + i) * srcld + nb + tx];
  __syncthreads();
#pragma unroll
  for (int i = ty; i < 32; i += 8) {
    int n = nb + i, drow = n;
    if (PERM) { const int j = n & 511, lvb = n >> 9; drow = ((j >> 4) << 5) | (lvb << 4) | (j & 15); }
    dst[(long)drow * K + kb + tx] = f2bf(t[tx][i]);
  }
}

__global__ void init_kernel(const float* __restrict__ ph, const float* __restrict__ ps,
                            float* __restrict__ out, short* __restrict__ hb, short* __restrict__ sb) {
  const int idx = blockIdx.x * 256 + threadIdx.x;
  const int b = idx >> 11, n = idx & 2047;
  const float h = ph[idx];
  out[(long)b * (Tsz * Hsz) + n] = h;
  hb[idx] = f2bf(h);
  if (n < Ssz) {
    const int sidx = b * Ssz + n;
    const float s = ps[sidx];
    out[OUT_PS + (long)b * (Tsz * Ssz) + n] = s;
    out[OUT_QS + (long)b * (Tsz * Ssz) + n] = s;
    sb[sidx] = f2bf(s);
  }
}

static GArg mk(const short* A, int lda, const short* Bt, int ldb, const float* bias,
               const short* Ci, long ldci, float* oF, int ldoF, long pstride,
               short* oB, int ldoB) {
  GArg g; g.A = A; g.Bt = Bt; g.bias = bias; g.Ci = Ci; g.ldci = ldci;
  g.oF = oF; g.oB = oB; g.lda = lda; g.ldb = ldb; g.ldoF = ldoF; g.ldoB = ldoB;
  g.pstride = pstride;
  return g;
}

extern "C" void kernel_launch(void* const* d_in, const int* in_sizes, int n_in,
                              void* d_out, int out_size, void* d_ws, size_t ws_size,
                              hipStream_t stream) {
  const float* prev_hidden = (const float*)d_in[0];
  const float* prev_state  = (const float*)d_in[1];
  const float* actions     = (const float*)d_in[2];
  const float* obs         = (const float*)d_in[3];
  const float* prior_noise = (const float*)d_in[4];
  const float* post_noise  = (const float*)d_in[5];
  const float* W_sa = (const float*)d_in[6];
  const float* b_sa = (const float*)d_in[7];
  const float* W_ih = (const float*)d_in[8];
  const float* W_hh = (const float*)d_in[9];
  const float* b_ih = (const float*)d_in[10];
  const float* b_hh = (const float*)d_in[11];
  const float* W_ha = (const float*)d_in[12];
  const float* b_ha = (const float*)d_in[13];
  const float* W_prior = (const float*)d_in[14];
  const float* b_prior = (const float*)d_in[15];
  const float* W_ho = (const float*)d_in[16];
  const float* b_ho = (const float*)d_in[17];
  const float* W_post = (const float*)d_in[18];
  const float* b_post = (const float*)d_in[19];
  float* out = (float*)d_out;

  char* p = (char*)d_ws;
  auto alloc = [&](size_t bytes) { char* r = p; p += (bytes + 255) & ~(size_t)255; return r; };
  short* Wih_p   = (short*)alloc(3L * Hsz * Hsz * 2);      // gate-permuted
  short* Whh_p   = (short*)alloc(3L * Hsz * Hsz * 2);
  short* Wt_sa_s = (short*)alloc((long)Hsz * Ssz * 2);
  short* Wt_sa_a = (short*)alloc((long)Hsz * Asz * 2);
  short* Wt_ha_h = (short*)alloc((long)Hsz * Hsz * 2);
  short* Wt_ha_a = (short*)alloc((long)Hsz * Asz * 2);
  short* Wt_ho_h = (short*)alloc((long)Hsz * Hsz * 2);
  short* Wt_ho_o = (short*)alloc((long)Hsz * Esz * 2);
  short* Wt_pr   = (short*)alloc(2L * Ssz * Hsz * 2);      // mean/lv interleaved
  short* Wt_po   = (short*)alloc(2L * Ssz * Hsz * 2);
  short* obs_b   = (short*)alloc((long)Bsz * Tsz * Esz * 2);
  short* act_b   = (short*)alloc((long)Bsz * Tsz * Asz * 2);
  short* a_pre   = (short*)alloc((long)Bsz * Tsz * Hsz * 2);
  short* ha_a    = (short*)alloc((long)Bsz * Tsz * Hsz * 2);
  short* ho_o    = (short*)alloc((long)Bsz * Tsz * Hsz * 2);
  short* s_b     = (short*)alloc((long)Bsz * Ssz * 2);
  short* h_b1    = (short*)alloc((long)Bsz * Hsz * 2);     // h ping-pong
  short* h_b2    = (short*)alloc((long)Bsz * Hsz * 2);
  short* sa_b    = (short*)alloc((long)Bsz * Hsz * 2);
  short* ha_b    = (short*)alloc((long)Bsz * Hsz * 2);
  short* ho_b    = (short*)alloc((long)Bsz * Hsz * 2);
  (void)ws_size; (void)in_sizes; (void)n_in; (void)out_size;

  // ---- setup ----------------------------------------------------------------
  conv_f2b<<<4096, 256, 0, stream>>>(obs,  obs_b, (long)Bsz * Tsz * Esz);
  conv_f2b<<<1024, 256, 0, stream>>>(actions, act_b, (long)Bsz * Tsz * Asz);
  conv_perm48<<<12288, 256, 0, stream>>>(W_ih, Wih_p);
  conv_perm48<<<12288, 256, 0, stream>>>(W_hh, Whh_p);

  dim3 tb(32, 8);
  transp<0><<<dim3(Hsz / 32, Ssz / 32), tb, 0, stream>>>(W_sa, Wt_sa_s, Hsz, 0,   Ssz, Hsz);
  transp<0><<<dim3(Hsz / 32, Asz / 32), tb, 0, stream>>>(W_sa, Wt_sa_a, Hsz, Ssz, Asz, Hsz);
  transp<0><<<dim3(Hsz / 32, Hsz / 32), tb, 0, stream>>>(W_ha, Wt_ha_h, Hsz, 0,   Hsz, Hsz);
  transp<0><<<dim3(Hsz / 32, Asz / 32), tb, 0, stream>>>(W_ha, Wt_ha_a, Hsz, Hsz, Asz, Hsz);
  transp<0><<<dim3(Hsz / 32, Hsz / 32), tb, 0, stream>>>(W_ho, Wt_ho_h, Hsz, 0,   Hsz, Hsz);
  transp<0><<<dim3(Hsz / 32, Esz / 32), tb, 0, stream>>>(W_ho, Wt_ho_o, Hsz, Hsz, Esz, Hsz);
  transp<1><<<dim3(2 * Ssz / 32, Hsz / 32), tb, 0, stream>>>(W_prior, Wt_pr, 2 * Ssz, 0, Hsz, 2 * Ssz);
  transp<1><<<dim3(2 * Ssz / 32, Hsz / 32), tb, 0, stream>>>(W_post,  Wt_po, 2 * Ssz, 0, Hsz, 2 * Ssz);

  init_kernel<<<2048, 256, 0, stream>>>(prev_hidden, prev_state, out, h_b1, s_b);

  // t-independent precomputes
  {
    GArg g0 = mk(act_b, Asz, Wt_sa_a, Asz, b_sa, nullptr, 0, nullptr, 0, 0, a_pre, Hsz);
    GArg g1 = mk(act_b, Asz, Wt_ha_a, Asz, b_ha, nullptr, 0, nullptr, 0, 0, ha_a, Hsz);
    gemm_bt<1, 0, 0, 0, 1><<<dim3(Hsz / 128, (Bsz * Tsz) / 128, 2), 256, 0, stream>>>(g0, g1, Asz);
  }
  {
    GArg g0 = mk(obs_b, Esz, Wt_ho_o, Esz, b_ho, nullptr, 0, nullptr, 0, 0, ho_o, Hsz);
    gemm_bt<1, 0, 0, 0, 1><<<dim3(Hsz / 128, (Bsz * Tsz) / 128, 1), 256, 0, stream>>>(g0, g0, Esz);
  }

  // ---- sequential scan: 4 dispatches / step, all many-small-block -----------
  const long ldPre = (long)Tsz * Hsz;
  for (int t = 0; t < TM1; ++t) {
    short* hp = (t & 1) ? h_b2 : h_b1;    // h_t
    short* hn = (t & 1) ? h_b1 : h_b2;    // h_{t+1}
    // 1) sa = relu(s @ Wsa_s^T + a_pre[t])          [256,2048] K=512, 32 blks
    {
      GArg g0 = mk(s_b, Ssz, Wt_sa_s, Ssz, nullptr, a_pre + (long)t * Hsz, ldPre,
                   nullptr, 0, 0, sa_b, Hsz);
      gemm_bt<0, 1, 1, 0, 1><<<dim3(16, 2, 1), 256, 0, stream>>>(g0, g0, Ssz);
    }
    // 2) gi+gh GEMMs + GRU fused -> h               [256,6144] K=2048, 256 blks
    gigh_gru<<<dim3(64, 4, 1), 256, 0, stream>>>(
        sa_b, hp, Wih_p, Whh_p, b_ih, b_hh,
        out + (long)t * Hsz, out + (long)(t + 1) * Hsz, hn);
    // 3) ha/ho 64x64-tiled, fused Ci+ReLU           [256,2048] K=2048, 256 blks
    haho64<<<dim3(32, 4, 2), 256, 0, stream>>>(
        hn, Wt_ha_h, Wt_ho_h, ha_a + (long)t * Hsz, ho_o + (long)t * Hsz, ldPre,
        ha_b, ho_b);
    // 4) prior/post 64x64-tiled + fused rsample     [256,1024] K=2048, 128 blks
    prpo_sample64<<<dim3(16, 4, 2), 256, 0, stream>>>(
        ha_b, ho_b, Wt_pr, Wt_po, b_prior, b_post,
        prior_noise, post_noise, out, s_b, t);
  }
}

// Round 11
// 6443.120 us; speedup vs baseline: 1.6451x; 1.1515x over previous
//
#include <hip/hip_runtime.h>

// ============================================================================
// RSSM (DynamicsModel) on MI355X — round 11.
// Diagnosis: all prior kernels ran <=1 block/CU with 4 BARRIER-LOCKED waves:
// the whole CU stalls at every vmcnt+s_barrier per K-iter (no resident waves
// to overlap).  Fix: BARRIER-FREE 1-wave blocks (64 thr) — each wave owns its
// LDS + K-chain, only wave-local vmcnt/lgkmcnt, 2+ independent waves/CU.
//   1. sa_w    (MI=4, 256 blks, nk=8, fused a_pre+ReLU)
//   2. gigh_gru (r7 exact, proven)
//   3. haho_w  (MI=4, 512 blks, nk=32, fused Ci+ReLU)
//   4. prpo_sample_w (MI=2, 512 blks, nk=32, fused rsample)
// ============================================================================

typedef __attribute__((ext_vector_type(8))) short bf16x8;
typedef __attribute__((ext_vector_type(4))) float f32x4;
typedef __attribute__((ext_vector_type(4))) short s16x4;

#define DEVI static __device__ __forceinline__

DEVI float bf2f(short s) { union { float f; unsigned u; } v; v.u = ((unsigned)(unsigned short)s) << 16; return v.f; }
DEVI short f2bf(float f) {
  union { float f; unsigned u; } v; v.f = f;
  unsigned r = v.u + 0x7FFFu + ((v.u >> 16) & 1u);   // RNE
  return (short)(r >> 16);
}

#define Bsz 256
#define Tsz 64
#define Hsz 2048
#define Ssz 512
#define Asz 64
#define Esz 2048
#define TM1 63

#define OUT_PS  33554432L
#define OUT_QS  41943040L
#define OUT_PM  50331648L
#define OUT_PLV 58589184L
#define OUT_QM  66846720L
#define OUT_QLV 75104256L

struct GArg {
  const short* A; const short* Bt; const float* bias; const short* Ci;
  float* oF; short* oB;
  int lda, ldb, ldoF, ldoB; long ldci, pstride;
};

// ---------------------------------------------------------------------------
// Barrier-free 1-wave GEMM: wave tile (MI*16) x 32, BK=64, dbuf LDS,
// wave-local vmcnt only.  Epilogue: + Ci (bf16), ReLU, bf16 out.
// grid: x = N/32, y = 256/(MI*16), z selects {0,1} operand set.
// ---------------------------------------------------------------------------
template<int MI>
__global__ __launch_bounds__(64) void gemm_w(
    const short* __restrict__ A0, const short* __restrict__ A1,
    const short* __restrict__ B0, const short* __restrict__ B1,
    const short* __restrict__ Ci0, const short* __restrict__ Ci1, long ldci,
    short* __restrict__ o0, short* __restrict__ o1,
    int lda, int ldb, int ldo, int nk) {
  const int z = blockIdx.z;
  const short* __restrict__ A  = z ? A1 : A0;
  const short* __restrict__ Bg = z ? B1 : B0;
  const short* __restrict__ Ci = z ? Ci1 : Ci0;
  short* __restrict__ o = z ? o1 : o0;
  __shared__ __align__(16) short As[2][MI * 1024];
  __shared__ __align__(16) short Bs[2][2048];
  const int l = threadIdx.x;
  const int bm0 = blockIdx.y * (MI * 16), bn0 = blockIdx.x << 5;
  const int fc = l & 15, fh = l >> 4, rx = fc & 7;
  const int srccol = ((l & 7) ^ ((l >> 3) & 7)) << 3;

  long aoff[2 * MI], boff[4];
#pragma unroll
  for (int i = 0; i < 2 * MI; ++i)
    aoff[i] = (long)(bm0 + (i << 3) + (l >> 3)) * lda + srccol;
#pragma unroll
  for (int i = 0; i < 4; ++i)
    boff[i] = (long)(bn0 + (i << 3) + (l >> 3)) * ldb + srccol;

  f32x4 acc[MI][2];
#pragma unroll
  for (int i = 0; i < MI; ++i)
#pragma unroll
    for (int j = 0; j < 2; ++j) acc[i][j] = f32x4{0.f, 0.f, 0.f, 0.f};

  auto STAGE = [&](int kt, int buf) {
#pragma unroll
    for (int i = 0; i < 2 * MI; ++i)
      __builtin_amdgcn_global_load_lds(
          (const __attribute__((address_space(1))) void*)(A + aoff[i] + (kt << 6)),
          (__attribute__((address_space(3))) void*)((char*)&As[buf][0] + (i << 10)), 16, 0, 0);
#pragma unroll
    for (int i = 0; i < 4; ++i)
      __builtin_amdgcn_global_load_lds(
          (const __attribute__((address_space(1))) void*)(Bg + boff[i] + (kt << 6)),
          (__attribute__((address_space(3))) void*)((char*)&Bs[buf][0] + (i << 10)), 16, 0, 0);
  };
  auto COMPUTE = [&](int buf) {
#pragma unroll
    for (int kk = 0; kk < 2; ++kk) {
      const int sw = (((kk << 2) + fh) ^ rx) << 3;
      bf16x8 af[MI], bb[2];
#pragma unroll
      for (int mi = 0; mi < MI; ++mi)
        af[mi] = *(const bf16x8*)&As[buf][((mi << 4) + fc) * 64 + sw];
#pragma unroll
      for (int ni = 0; ni < 2; ++ni)
        bb[ni] = *(const bf16x8*)&Bs[buf][((ni << 4) + fc) * 64 + sw];
#pragma unroll
      for (int mi = 0; mi < MI; ++mi)
#pragma unroll
        for (int ni = 0; ni < 2; ++ni)
          acc[mi][ni] = __builtin_amdgcn_mfma_f32_16x16x32_bf16(af[mi], bb[ni], acc[mi][ni], 0, 0, 0);
    }
  };

  STAGE(0, 0);
  for (int kt = 0; kt < nk; ++kt) {
    if (kt + 1 < nk) {
      STAGE(kt + 1, (kt + 1) & 1);
      asm volatile("s_waitcnt vmcnt(%0)" :: "i"(2 * MI + 4) : "memory");
    } else {
      asm volatile("s_waitcnt vmcnt(0)" ::: "memory");
    }
    __builtin_amdgcn_sched_barrier(0);
    COMPUTE(kt & 1);
    asm volatile("s_waitcnt lgkmcnt(0)" ::: "memory");
    __builtin_amdgcn_sched_barrier(0);
  }

#pragma unroll
  for (int mi = 0; mi < MI; ++mi) {
#pragma unroll
    for (int ni = 0; ni < 2; ++ni) {
      const int n = bn0 + (ni << 4) + fc;
#pragma unroll
      for (int r = 0; r < 4; ++r) {
        const int m = bm0 + (mi << 4) + (fh << 2) + r;
        const float v = acc[mi][ni][r] + bf2f(Ci[(long)m * ldci + n]);
        o[(long)m * ldo + n] = f2bf(fmaxf(v, 0.f));
      }
    }
  }
}

// ---------------------------------------------------------------------------
// Barrier-free 1-wave prior/post GEMM + fused rsample.  Tile 32x32, B is
// column-interleaved (row' = (j>>4)*32 + lv*16 + (j&15)): ni=0 -> mean,
// ni=1 -> logvar of state j = (bn0>>5)*16 + fc.  grid (32, 8, 2); z=1 also
// writes s_b.
// ---------------------------------------------------------------------------
__global__ __launch_bounds__(64) void prpo_sample_w(
    const short* __restrict__ A0, const short* __restrict__ A1,
    const short* __restrict__ B0, const short* __restrict__ B1,
    const float* __restrict__ bi0, const float* __restrict__ bi1,
    const float* __restrict__ n0, const float* __restrict__ n1,
    float* __restrict__ out, short* __restrict__ sb, int t) {
  const int z = blockIdx.z;
  const short* __restrict__ A  = z ? A1 : A0;
  const short* __restrict__ Bg = z ? B1 : B0;
  const float* __restrict__ bias = z ? bi1 : bi0;
  const float* __restrict__ noise = z ? n1 : n0;
  const long oS = z ? OUT_QS : OUT_PS, oM = z ? OUT_QM : OUT_PM, oLV = z ? OUT_QLV : OUT_PLV;
  __shared__ __align__(16) short As[2][2048];
  __shared__ __align__(16) short Bs[2][2048];
  const int l = threadIdx.x;
  const int bm0 = blockIdx.y << 5, bn0 = blockIdx.x << 5;
  const int fc = l & 15, fh = l >> 4, rx = fc & 7;
  const int srccol = ((l & 7) ^ ((l >> 3) & 7)) << 3;

  long aoff[4], boff[4];
#pragma unroll
  for (int i = 0; i < 4; ++i) {
    const int row = (i << 3) + (l >> 3);
    aoff[i] = (long)(bm0 + row) * Hsz + srccol;
    boff[i] = (long)(bn0 + row) * Hsz + srccol;
  }

  f32x4 acc[2][2];
#pragma unroll
  for (int i = 0; i < 2; ++i)
#pragma unroll
    for (int j = 0; j < 2; ++j) acc[i][j] = f32x4{0.f, 0.f, 0.f, 0.f};

  auto STAGE = [&](int kt, int buf) {
#pragma unroll
    for (int i = 0; i < 4; ++i) {
      __builtin_amdgcn_global_load_lds(
          (const __attribute__((address_space(1))) void*)(A + aoff[i] + (kt << 6)),
          (__attribute__((address_space(3))) void*)((char*)&As[buf][0] + (i << 10)), 16, 0, 0);
      __builtin_amdgcn_global_load_lds(
          (const __attribute__((address_space(1))) void*)(Bg + boff[i] + (kt << 6)),
          (__attribute__((address_space(3))) void*)((char*)&Bs[buf][0] + (i << 10)), 16, 0, 0);
    }
  };
  auto COMPUTE = [&](int buf) {
#pragma unroll
    for (int kk = 0; kk < 2; ++kk) {
      const int sw = (((kk << 2) + fh) ^ rx) << 3;
      bf16x8 af[2], bb[2];
#pragma unroll
      for (int mi = 0; mi < 2; ++mi)
        af[mi] = *(const bf16x8*)&As[buf][((mi << 4) + fc) * 64 + sw];
#pragma unroll
      for (int ni = 0; ni < 2; ++ni)
        bb[ni] = *(const bf16x8*)&Bs[buf][((ni << 4) + fc) * 64 + sw];
#pragma unroll
      for (int mi = 0; mi < 2; ++mi)
#pragma unroll
        for (int ni = 0; ni < 2; ++ni)
          acc[mi][ni] = __builtin_amdgcn_mfma_f32_16x16x32_bf16(af[mi], bb[ni], acc[mi][ni], 0, 0, 0);
    }
  };

  const int nk = Hsz >> 6;   // 32
  STAGE(0, 0);
  for (int kt = 0; kt < nk; ++kt) {
    if (kt + 1 < nk) {
      STAGE(kt + 1, (kt + 1) & 1);
      asm volatile("s_waitcnt vmcnt(8)" ::: "memory");
    } else {
      asm volatile("s_waitcnt vmcnt(0)" ::: "memory");
    }
    __builtin_amdgcn_sched_barrier(0);
    COMPUTE(kt & 1);
    asm volatile("s_waitcnt lgkmcnt(0)" ::: "memory");
    __builtin_amdgcn_sched_barrier(0);
  }

  const int j = ((bn0 >> 5) << 4) + fc;   // [0,512)
  const float bm_ = bias[j], blv = bias[512 + j];
#pragma unroll
  for (int mi = 0; mi < 2; ++mi) {
#pragma unroll
    for (int r = 0; r < 4; ++r) {
      const int b = bm0 + (mi << 4) + (fh << 2) + r;
      const float mv = acc[mi][0][r] + bm_;
      const float lv = acc[mi][1][r] + blv;
      const long noff = ((long)b * TM1 + t) * Ssz + j;
      const float sv = mv + (1.f + expf(lv)) * noise[noff];
      out[oS + (long)b * (Tsz * Ssz) + (long)(t + 1) * Ssz + j] = sv;
      out[oM + noff] = mv;
      out[oLV + noff] = lv;
      if (z) sb[b * Ssz + j] = f2bf(sv);
    }
  }
}

// ---------------------------------------------------------------------------
// throughput GEMM (r2-proven): 128x128, BK=64 — precomputes only.
// ---------------------------------------------------------------------------
template<int HASBIAS, int HASCI, int RELU, int OUTF, int OUTB>
__global__ __launch_bounds__(256) void gemm_bt(GArg g0, GArg g1, int kcK) {
  const int gemm = blockIdx.z & 1;
  const GArg g = gemm ? g1 : g0;
  const short* __restrict__ Ag = g.A;
  const short* __restrict__ Bg = g.Bt;
  __shared__ __align__(16) short As[2][8192];
  __shared__ __align__(16) short Bs[2][8192];
  const int tid = threadIdx.x;
  const int w = tid >> 6, l = tid & 63;
  const int bm0 = blockIdx.y << 7, bn0 = blockIdx.x << 7;
  const int fc = l & 15, fh = l >> 4;
  const int wr = (w >> 1) << 6, wc = (w & 1) << 6;
  const int rx = fc & 7;
  const int srccol = ((l & 7) ^ ((l >> 3) & 7)) << 3;
  long aoff[4], boff[4];
#pragma unroll
  for (int i = 0; i < 4; ++i) {
    const int row = (((i << 2) + w) << 3) + (l >> 3);
    aoff[i] = (long)(bm0 + row) * g.lda + srccol;
    boff[i] = (long)(bn0 + row) * g.ldb + srccol;
  }
  f32x4 acc[4][4];
#pragma unroll
  for (int i = 0; i < 4; ++i)
#pragma unroll
    for (int j = 0; j < 4; ++j) acc[i][j] = f32x4{0.f, 0.f, 0.f, 0.f};

  auto STAGE = [&](int kt, int buf) {
#pragma unroll
    for (int i = 0; i < 4; ++i) {
      const int ib = ((i << 2) + w) << 10;
      __builtin_amdgcn_global_load_lds(
          (const __attribute__((address_space(1))) void*)(Ag + aoff[i] + (kt << 6)),
          (__attribute__((address_space(3))) void*)((char*)&As[buf][0] + ib), 16, 0, 0);
      __builtin_amdgcn_global_load_lds(
          (const __attribute__((address_space(1))) void*)(Bg + boff[i] + (kt << 6)),
          (__attribute__((address_space(3))) void*)((char*)&Bs[buf][0] + ib), 16, 0, 0);
    }
  };
  auto COMPUTE = [&](int buf) {
#pragma unroll
    for (int kk = 0; kk < 2; ++kk) {
      bf16x8 af[4], bb[4];
#pragma unroll
      for (int mi = 0; mi < 4; ++mi)
        af[mi] = *(const bf16x8*)&As[buf][(wr + (mi << 4) + fc) * 64 + ((((kk << 2) + fh) ^ rx) << 3)];
#pragma unroll
      for (int ni = 0; ni < 4; ++ni)
        bb[ni] = *(const bf16x8*)&Bs[buf][(wc + (ni << 4) + fc) * 64 + ((((kk << 2) + fh) ^ rx) << 3)];
#pragma unroll
      for (int mi = 0; mi < 4; ++mi)
#pragma unroll
        for (int ni = 0; ni < 4; ++ni)
          acc[mi][ni] = __builtin_amdgcn_mfma_f32_16x16x32_bf16(af[mi], bb[ni], acc[mi][ni], 0, 0, 0);
    }
  };

  const int nk = kcK >> 6;
  STAGE(0, 0);
  for (int kt = 0; kt < nk - 1; ++kt) {
    STAGE(kt + 1, (kt + 1) & 1);
    asm volatile("s_waitcnt vmcnt(8)" ::: "memory");
    __builtin_amdgcn_s_barrier();
    __builtin_amdgcn_sched_barrier(0);
    COMPUTE(kt & 1);
    asm volatile("s_waitcnt lgkmcnt(0)" ::: "memory");
    __builtin_amdgcn_s_barrier();
  }
  asm volatile("s_waitcnt vmcnt(0)" ::: "memory");
  __builtin_amdgcn_s_barrier();
  __builtin_amdgcn_sched_barrier(0);
  COMPUTE((nk - 1) & 1);

#pragma unroll
  for (int mi = 0; mi < 4; ++mi) {
#pragma unroll
    for (int ni = 0; ni < 4; ++ni) {
      const int n = bn0 + wc + (ni << 4) + fc;
      float bv = 0.f;
      if (HASBIAS) bv = g.bias[n];
#pragma unroll
      for (int r = 0; r < 4; ++r) {
        const int m = bm0 + wr + (mi << 4) + (fh << 2) + r;
        float v = acc[mi][ni][r] + bv;
        if (HASCI) v += bf2f(g.Ci[(long)m * g.ldci + n]);
        if (RELU) v = fmaxf(v, 0.f);
        if (OUTF) g.oF[(long)m * g.ldoF + n] = v;
        if (OUTB) g.oB[(long)m * g.ldoB + n] = f2bf(v);
      }
    }
  }
}

// ---------------------------------------------------------------------------
// gi+gh+GRU fused (r7 EXACT, proven).
// ---------------------------------------------------------------------------
__global__ __launch_bounds__(256) void gigh_gru(
    const short* __restrict__ sa, const short* __restrict__ hb_in,
    const short* __restrict__ Wih, const short* __restrict__ Whh,
    const float* __restrict__ b_ih, const float* __restrict__ b_hh,
    const float* __restrict__ hold, float* __restrict__ hnew,
    short* __restrict__ hb_out) {
  __shared__ __align__(16) short AsS[2][4096];
  __shared__ __align__(16) short AsH[2][4096];
  __shared__ __align__(16) short BsI[2][6144];
  __shared__ __align__(16) short BsH[2][6144];
  const int tid = threadIdx.x;
  const int w = tid >> 6, l = tid & 63;
  const int bm0 = blockIdx.y << 6;
  const int bn0 = blockIdx.x * 96;
  const int fc = l & 15, fh = l >> 4;
  const int wr = (w >> 1) << 5;
  const int wn = (w & 1) * 48;
  const int rx = fc & 7;
  const int srccol = ((l & 7) ^ ((l >> 3) & 7)) << 3;

  long aoff[2], boff[3];
#pragma unroll
  for (int i = 0; i < 2; ++i) {
    const int row = (((i << 2) + w) << 3) + (l >> 3);
    aoff[i] = (long)(bm0 + row) * Hsz + srccol;
  }
#pragma unroll
  for (int i = 0; i < 3; ++i) {
    const int row = (((i << 2) + w) << 3) + (l >> 3);
    boff[i] = (long)(bn0 + row) * Hsz + srccol;
  }

  f32x4 acc_i[2][3], acc_h[2][3];
#pragma unroll
  for (int i = 0; i < 2; ++i)
#pragma unroll
    for (int j = 0; j < 3; ++j) { acc_i[i][j] = f32x4{0.f,0.f,0.f,0.f}; acc_h[i][j] = f32x4{0.f,0.f,0.f,0.f}; }

  auto STAGE = [&](int kt, int buf) {
#pragma unroll
    for (int i = 0; i < 2; ++i) {
      const int ib = ((i << 2) + w) << 10;
      __builtin_amdgcn_global_load_lds(
          (const __attribute__((address_space(1))) void*)(sa + aoff[i] + (kt << 6)),
          (__attribute__((address_space(3))) void*)((char*)&AsS[0][0] + (buf << 13) + ib), 16, 0, 0);
      __builtin_amdgcn_global_load_lds(
          (const __attribute__((address_space(1))) void*)(hb_in + aoff[i] + (kt << 6)),
          (__attribute__((address_space(3))) void*)((char*)&AsH[0][0] + (buf << 13) + ib), 16, 0, 0);
    }
#pragma unroll
    for (int i = 0; i < 3; ++i) {
      const int ib = ((i << 2) + w) << 10;
      __builtin_amdgcn_global_load_lds(
          (const __attribute__((address_space(1))) void*)(Wih + boff[i] + (kt << 6)),
          (__attribute__((address_space(3))) void*)((char*)&BsI[0][0] + buf * 12288 + ib), 16, 0, 0);
      __builtin_amdgcn_global_load_lds(
          (const __attribute__((address_space(1))) void*)(Whh + boff[i] + (kt << 6)),
          (__attribute__((address_space(3))) void*)((char*)&BsH[0][0] + buf * 12288 + ib), 16, 0, 0);
    }
  };
  auto COMPUTE = [&](int buf) {
#pragma unroll
    for (int kk = 0; kk < 2; ++kk) {
      const int sw = (((kk << 2) + fh) ^ rx) << 3;
      bf16x8 as_[2], ah_[2], bi_[3], bh_[3];
#pragma unroll
      for (int mi = 0; mi < 2; ++mi) {
        as_[mi] = *(const bf16x8*)&AsS[buf][(wr + (mi << 4) + fc) * 64 + sw];
        ah_[mi] = *(const bf16x8*)&AsH[buf][(wr + (mi << 4) + fc) * 64 + sw];
      }
#pragma unroll
      for (int ni = 0; ni < 3; ++ni) {
        bi_[ni] = *(const bf16x8*)&BsI[buf][(wn + (ni << 4) + fc) * 64 + sw];
        bh_[ni] = *(const bf16x8*)&BsH[buf][(wn + (ni << 4) + fc) * 64 + sw];
      }
#pragma unroll
      for (int mi = 0; mi < 2; ++mi)
#pragma unroll
        for (int ni = 0; ni < 3; ++ni) {
          acc_i[mi][ni] = __builtin_amdgcn_mfma_f32_16x16x32_bf16(as_[mi], bi_[ni], acc_i[mi][ni], 0, 0, 0);
          acc_h[mi][ni] = __builtin_amdgcn_mfma_f32_16x16x32_bf16(ah_[mi], bh_[ni], acc_h[mi][ni], 0, 0, 0);
        }
    }
  };

  const int nk = Hsz >> 6;
  STAGE(0, 0);
  for (int kt = 0; kt < nk - 1; ++kt) {
    STAGE(kt + 1, (kt + 1) & 1);
    asm volatile("s_waitcnt vmcnt(10)" ::: "memory");
    __builtin_amdgcn_s_barrier();
    __builtin_amdgcn_sched_barrier(0);
    COMPUTE(kt & 1);
    asm volatile("s_waitcnt lgkmcnt(0)" ::: "memory");
    __builtin_amdgcn_s_barrier();
  }
  asm volatile("s_waitcnt vmcnt(0)" ::: "memory");
  __builtin_amdgcn_s_barrier();
  __builtin_amdgcn_sched_barrier(0);
  COMPUTE((nk - 1) & 1);

  const int j = (((int)blockIdx.x << 1) + (w & 1)) * 16 + fc;
  const float bir = b_ih[j],            bhr = b_hh[j];
  const float biz = b_ih[Hsz + j],      bhz = b_hh[Hsz + j];
  const float bin = b_ih[2 * Hsz + j],  bhn = b_hh[2 * Hsz + j];
#pragma unroll
  for (int mi = 0; mi < 2; ++mi) {
#pragma unroll
    for (int r = 0; r < 4; ++r) {
      const int m = bm0 + wr + (mi << 4) + (fh << 2) + r;
      const float ir = acc_i[mi][0][r] + bir, hr = acc_h[mi][0][r] + bhr;
      const float iz = acc_i[mi][1][r] + biz, hz = acc_h[mi][1][r] + bhz;
      const float in_ = acc_i[mi][2][r] + bin, hn = acc_h[mi][2][r] + bhn;
      const float rg = 1.f / (1.f + expf(-(ir + hr)));
      const float zg = 1.f / (1.f + expf(-(iz + hz)));
      const float ng = tanhf(in_ + rg * hn);
      const float hv = (1.f - zg) * ng + zg * hold[(long)m * (Tsz * Hsz) + j];
      hnew[(long)m * (Tsz * Hsz) + j] = hv;
      hb_out[m * Hsz + j] = f2bf(hv);
    }
  }
}

// ---------------------------------------------------------------------------
// small kernels
// ---------------------------------------------------------------------------
__global__ void conv_f2b(const float* __restrict__ src, short* __restrict__ dst, long n) {
  long i = ((long)blockIdx.x * 256 + threadIdx.x) * 4;
  const long stride = (long)gridDim.x * 1024;
  for (; i < n; i += stride) {
    float4 v = *(const float4*)(src + i);
    s16x4 o;
    o[0] = f2bf(v.x); o[1] = f2bf(v.y); o[2] = f2bf(v.z); o[3] = f2bf(v.w);
    *(s16x4*)(dst + i) = o;
  }
}

__global__ void conv_perm48(const float* __restrict__ src, short* __restrict__ dst) {
  const long e = ((long)blockIdx.x * 256 + threadIdx.x) * 4;
  const int np = (int)(e >> 11), col = (int)(e & 2047);
  const int u = np / 48, rem = np - u * 48;
  const int g = rem >> 4, jlo = rem & 15;
  const long srow = ((long)g << 11) + u * 16 + jlo;
  float4 v = *(const float4*)&src[srow * 2048 + col];
  s16x4 o;
  o[0] = f2bf(v.x); o[1] = f2bf(v.y); o[2] = f2bf(v.z); o[3] = f2bf(v.w);
  *(s16x4*)&dst[e] = o;
}

template<int PERM>
__global__ void transp(const float* __restrict__ src, short* __restrict__ dst,
                       int srcld, int k0, int K, int N) {
  __shared__ float t[32][33];
  const int tx = threadIdx.x, ty = threadIdx.y;
  const int kb = blockIdx.y << 5, nb = blockIdx.x << 5;
#pragma unroll
  for (int i = ty; i < 32; i += 8)
    t[i][tx] = src[(long)(k0 + kb + i) * srcld + nb + tx];
  __syncthreads();
#pragma unroll
  for (int i = ty; i < 32; i += 8) {
    int n = nb + i, drow = n;
    if (PERM) { const int j = n & 511, lvb = n >> 9; drow = ((j >> 4) << 5) | (lvb << 4) | (j & 15); }
    dst[(long)drow * K + kb + tx] = f2bf(t[tx][i]);
  }
}

__global__ void init_kernel(const float* __restrict__ ph, const float* __restrict__ ps,
                            float* __restrict__ out, short* __restrict__ hb, short* __restrict__ sb) {
  const int idx = blockIdx.x * 256 + threadIdx.x;
  const int b = idx >> 11, n = idx & 2047;
  const float h = ph[idx];
  out[(long)b * (Tsz * Hsz) + n] = h;
  hb[idx] = f2bf(h);
  if (n < Ssz) {
    const int sidx = b * Ssz + n;
    const float s = ps[sidx];
    out[OUT_PS + (long)b * (Tsz * Ssz) + n] = s;
    out[OUT_QS + (long)b * (Tsz * Ssz) + n] = s;
    sb[sidx] = f2bf(s);
  }
}

static GArg mk(const short* A, int lda, const short* Bt, int ldb, const float* bias,
               const short* Ci, long ldci, float* oF, int ldoF, long pstride,
               short* oB, int ldoB) {
  GArg g; g.A = A; g.Bt = Bt; g.bias = bias; g.Ci = Ci; g.ldci = ldci;
  g.oF = oF; g.oB = oB; g.lda = lda; g.ldb = ldb; g.ldoF = ldoF; g.ldoB = ldoB;
  g.pstride = pstride;
  return g;
}

extern "C" void kernel_launch(void* const* d_in, const int* in_sizes, int n_in,
                              void* d_out, int out_size, void* d_ws, size_t ws_size,
                              hipStream_t stream) {
  const float* prev_hidden = (const float*)d_in[0];
  const float* prev_state  = (const float*)d_in[1];
  const float* actions     = (const float*)d_in[2];
  const float* obs         = (const float*)d_in[3];
  const float* prior_noise = (const float*)d_in[4];
  const float* post_noise  = (const float*)d_in[5];
  const float* W_sa = (const float*)d_in[6];
  const float* b_sa = (const float*)d_in[7];
  const float* W_ih = (const float*)d_in[8];
  const float* W_hh = (const float*)d_in[9];
  const float* b_ih = (const float*)d_in[10];
  const float* b_hh = (const float*)d_in[11];
  const float* W_ha = (const float*)d_in[12];
  const float* b_ha = (const float*)d_in[13];
  const float* W_prior = (const float*)d_in[14];
  const float* b_prior = (const float*)d_in[15];
  const float* W_ho = (const float*)d_in[16];
  const float* b_ho = (const float*)d_in[17];
  const float* W_post = (const float*)d_in[18];
  const float* b_post = (const float*)d_in[19];
  float* out = (float*)d_out;

  char* p = (char*)d_ws;
  auto alloc = [&](size_t bytes) { char* r = p; p += (bytes + 255) & ~(size_t)255; return r; };
  short* Wih_p   = (short*)alloc(3L * Hsz * Hsz * 2);      // gate-permuted
  short* Whh_p   = (short*)alloc(3L * Hsz * Hsz * 2);
  short* Wt_sa_s = (short*)alloc((long)Hsz * Ssz * 2);
  short* Wt_sa_a = (short*)alloc((long)Hsz * Asz * 2);
  short* Wt_ha_h = (short*)alloc((long)Hsz * Hsz * 2);
  short* Wt_ha_a = (short*)alloc((long)Hsz * Asz * 2);
  short* Wt_ho_h = (short*)alloc((long)Hsz * Hsz * 2);
  short* Wt_ho_o = (short*)alloc((long)Hsz * Esz * 2);
  short* Wt_pr   = (short*)alloc(2L * Ssz * Hsz * 2);      // mean/lv interleaved
  short* Wt_po   = (short*)alloc(2L * Ssz * Hsz * 2);
  short* obs_b   = (short*)alloc((long)Bsz * Tsz * Esz * 2);
  short* act_b   = (short*)alloc((long)Bsz * Tsz * Asz * 2);
  short* a_pre   = (short*)alloc((long)Bsz * Tsz * Hsz * 2);
  short* ha_a    = (short*)alloc((long)Bsz * Tsz * Hsz * 2);
  short* ho_o    = (short*)alloc((long)Bsz * Tsz * Hsz * 2);
  short* s_b     = (short*)alloc((long)Bsz * Ssz * 2);
  short* h_b1    = (short*)alloc((long)Bsz * Hsz * 2);     // h ping-pong
  short* h_b2    = (short*)alloc((long)Bsz * Hsz * 2);
  short* sa_b    = (short*)alloc((long)Bsz * Hsz * 2);
  short* ha_b    = (short*)alloc((long)Bsz * Hsz * 2);
  short* ho_b    = (short*)alloc((long)Bsz * Hsz * 2);
  (void)ws_size; (void)in_sizes; (void)n_in; (void)out_size;

  // ---- setup ----------------------------------------------------------------
  conv_f2b<<<4096, 256, 0, stream>>>(obs,  obs_b, (long)Bsz * Tsz * Esz);
  conv_f2b<<<1024, 256, 0, stream>>>(actions, act_b, (long)Bsz * Tsz * Asz);
  conv_perm48<<<12288, 256, 0, stream>>>(W_ih, Wih_p);
  conv_perm48<<<12288, 256, 0, stream>>>(W_hh, Whh_p);

  dim3 tb(32, 8);
  transp<0><<<dim3(Hsz / 32, Ssz / 32), tb, 0, stream>>>(W_sa, Wt_sa_s, Hsz, 0,   Ssz, Hsz);
  transp<0><<<dim3(Hsz / 32, Asz / 32), tb, 0, stream>>>(W_sa, Wt_sa_a, Hsz, Ssz, Asz, Hsz);
  transp<0><<<dim3(Hsz / 32, Hsz / 32), tb, 0, stream>>>(W_ha, Wt_ha_h, Hsz, 0,   Hsz, Hsz);
  transp<0><<<dim3(Hsz / 32, Asz / 32), tb, 0, stream>>>(W_ha, Wt_ha_a, Hsz, Hsz, Asz, Hsz);
  transp<0><<<dim3(Hsz / 32, Hsz / 32), tb, 0, stream>>>(W_ho, Wt_ho_h, Hsz, 0,   Hsz, Hsz);
  transp<0><<<dim3(Hsz / 32, Esz / 32), tb, 0, stream>>>(W_ho, Wt_ho_o, Hsz, Hsz, Esz, Hsz);
  transp<1><<<dim3(2 * Ssz / 32, Hsz / 32), tb, 0, stream>>>(W_prior, Wt_pr, 2 * Ssz, 0, Hsz, 2 * Ssz);
  transp<1><<<dim3(2 * Ssz / 32, Hsz / 32), tb, 0, stream>>>(W_post,  Wt_po, 2 * Ssz, 0, Hsz, 2 * Ssz);

  init_kernel<<<2048, 256, 0, stream>>>(prev_hidden, prev_state, out, h_b1, s_b);

  // t-independent precomputes
  {
    GArg g0 = mk(act_b, Asz, Wt_sa_a, Asz, b_sa, nullptr, 0, nullptr, 0, 0, a_pre, Hsz);
    GArg g1 = mk(act_b, Asz, Wt_ha_a, Asz, b_ha, nullptr, 0, nullptr, 0, 0, ha_a, Hsz);
    gemm_bt<1, 0, 0, 0, 1><<<dim3(Hsz / 128, (Bsz * Tsz) / 128, 2), 256, 0, stream>>>(g0, g1, Asz);
  }
  {
    GArg g0 = mk(obs_b, Esz, Wt_ho_o, Esz, b_ho, nullptr, 0, nullptr, 0, 0, ho_o, Hsz);
    gemm_bt<1, 0, 0, 0, 1><<<dim3(Hsz / 128, (Bsz * Tsz) / 128, 1), 256, 0, stream>>>(g0, g0, Esz);
  }

  // ---- sequential scan: 4 dispatches / step, barrier-free wave kernels ------
  const long ldPre = (long)Tsz * Hsz;
  for (int t = 0; t < TM1; ++t) {
    short* hp = (t & 1) ? h_b2 : h_b1;    // h_t
    short* hn = (t & 1) ? h_b1 : h_b2;    // h_{t+1}
    // 1) sa = relu(s @ Wsa_s^T + a_pre[t])      [256,2048] K=512, 256 1-wave blks
    gemm_w<4><<<dim3(64, 4, 1), 64, 0, stream>>>(
        s_b, s_b, Wt_sa_s, Wt_sa_s, a_pre + (long)t * Hsz, a_pre + (long)t * Hsz,
        ldPre, sa_b, sa_b, Ssz, Ssz, Hsz, Ssz / 64);
    // 2) gi+gh GEMMs + GRU fused -> h           [256,6144] K=2048, 256 blks
    gigh_gru<<<dim3(64, 4, 1), 256, 0, stream>>>(
        sa_b, hp, Wih_p, Whh_p, b_ih, b_hh,
        out + (long)t * Hsz, out + (long)(t + 1) * Hsz, hn);
    // 3) ha/ho fused Ci+ReLU                    [256,2048] K=2048, 512 1-wave blks
    gemm_w<4><<<dim3(64, 4, 2), 64, 0, stream>>>(
        hn, hn, Wt_ha_h, Wt_ho_h, ha_a + (long)t * Hsz, ho_o + (long)t * Hsz,
        ldPre, ha_b, ho_b, Hsz, Hsz, Hsz, Hsz / 64);
    // 4) prior/post GEMM + fused rsample        [256,1024] K=2048, 512 1-wave blks
    prpo_sample_w<<<dim3(32, 8, 2), 64, 0, stream>>>(
        ha_b, ho_b, Wt_pr, Wt_po, b_prior, b_post,
        prior_noise, post_noise, out, s_b, t);
  }
}